// Round 1
// baseline (772.698 us; speedup 1.0000x reference)
//
#include <hip/hip_runtime.h>
#include <math.h>

#define B_ 16
#define N_ 4096
#define M_ 1024
#define C1_ 256
#define C2_ 512
#define H_ 256
#define SEC_ 10
#define BN_EPS 1e-5f

// ---------------------------------------------------------------------------
// K1: three_nn — per (b,n) find 3 smallest squared distances to known[b]
// ---------------------------------------------------------------------------
__global__ __launch_bounds__(256)
void three_nn_kernel(const float* __restrict__ unknown, const float* __restrict__ known,
                     int* __restrict__ idxp, float* __restrict__ wgtp)
{
    __shared__ float kx[M_], ky[M_], kz[M_];
    const int b = blockIdx.y;
    const float* kb = known + (long)b * M_ * 3;
    for (int i = threadIdx.x; i < M_; i += 256) {
        kx[i] = kb[i*3+0]; ky[i] = kb[i*3+1]; kz[i] = kb[i*3+2];
    }
    __syncthreads();
    const int n = blockIdx.x * 256 + threadIdx.x;
    const float* up = unknown + ((long)b * N_ + n) * 3;
    const float ux = up[0], uy = up[1], uz = up[2];
    float b0 = 1e30f, b1v = 1e30f, b2v = 1e30f;
    int j0 = 0, j1 = 0, j2 = 0;
    for (int m = 0; m < M_; m++) {
        const float dx = ux - kx[m], dy = uy - ky[m], dz = uz - kz[m];
        const float d = dx*dx + dy*dy + dz*dz;
        if (d < b2v) {
            if (d < b1v) {
                b2v = b1v; j2 = j1;
                if (d < b0) { b1v = b0; j1 = j0; b0 = d; j0 = m; }
                else        { b1v = d;  j1 = m; }
            } else { b2v = d; j2 = m; }
        }
    }
    const float r0 = 1.f/(b0 + 1e-8f), r1 = 1.f/(b1v + 1e-8f), r2 = 1.f/(b2v + 1e-8f);
    const float rs = 1.f/(r0 + r1 + r2);
    const long base = ((long)b * N_ + n) * 3;
    idxp[base+0] = j0; idxp[base+1] = j1; idxp[base+2] = j2;
    wgtp[base+0] = r0*rs; wgtp[base+1] = r1*rs; wgtp[base+2] = r2*rs;
}

// ---------------------------------------------------------------------------
// Tiled fp32 GEMM:  C[b] = A @ B[b]   (A: [Mrows x K] row-major shared, B: per-batch [K x Ncols])
// MODE 0: plain store (G = W1a @ kf)
// MODE 1: epilogue adds 3-NN gather-combine from G, stores h1, accumulates BN stats
// MODE 2: B-staging applies SE gate: X = sigmoid(ew@ssw+eb) * (a1*h1+c1); stats on output
// ---------------------------------------------------------------------------
template<int BM, int BN, int BK, int TM, int TN, int MODE>
__global__ __launch_bounds__(256)
void gemm_f32(const float* __restrict__ A, int lda,
              const float* __restrict__ Bmat, long strideB, int ldb,
              float* __restrict__ C, long strideC, int ldc, int K,
              const float* __restrict__ Gp, long strideG,
              const int* __restrict__ idxp, const float* __restrict__ wgtp,
              float* __restrict__ stats,
              const float* __restrict__ spart, const float* __restrict__ rbAdj,
              const float* __restrict__ se_ewp, const float* __restrict__ se_ebp,
              const float* __restrict__ a1p, const float* __restrict__ c1p)
{
    constexpr int THREADS = (BM/TM)*(BN/TN);
    static_assert(THREADS == 256, "block must be 256 threads");
    __shared__ float As[BK][BM];
    __shared__ float Bs[BK][BN];
    __shared__ float sswl[SEC_][BN];   // only used by MODE 2

    const int b  = blockIdx.z;
    const int bm = blockIdx.y * BM;
    const int bn = blockIdx.x * BN;
    const int tid = threadIdx.x;
    const int tx = tid % (BN/TN);
    const int ty = tid / (BN/TN);

    const float* Bb = Bmat + (long)b * strideB;

    // staging geometry
    constexpr int A_PER_T = BM*BK/THREADS;        // floats per thread (A tile)
    constexpr int A_TPR   = BK / A_PER_T;         // threads per A row
    const int a_o = tid / A_TPR;
    const int a_k = (tid % A_TPR) * A_PER_T;
    constexpr int B_PER_T = BK*BN/THREADS;        // floats per thread (B tile)
    constexpr int B_TPR   = BN / B_PER_T;         // threads per B row
    const int b_k = tid / B_TPR;
    const int b_n = (tid % B_TPR) * B_PER_T;

    if constexpr (MODE == 2) {
        // build swish(s) for this block's n-range once: ssw[j][n]
        for (int i = tid; i < SEC_*BN; i += THREADS) {
            const int j = i / BN, n = i % BN;
            float v = spart[((long)0*B_ + b)*SEC_*N_ + (long)j*N_ + bn + n]
                    + spart[((long)1*B_ + b)*SEC_*N_ + (long)j*N_ + bn + n]
                    + rbAdj[j];
            sswl[j][n] = v / (1.f + __expf(-v));   // swish
        }
        __syncthreads();
    }

    float acc[TM][TN];
    #pragma unroll
    for (int i = 0; i < TM; i++)
        #pragma unroll
        for (int j = 0; j < TN; j++) acc[i][j] = 0.f;

    for (int k0 = 0; k0 < K; k0 += BK) {
        // ---- stage A (transposed to As[k][o]) ----
        #pragma unroll
        for (int c = 0; c < A_PER_T; c += 4) {
            const float4 v = *(const float4*)(A + (long)(bm + a_o)*lda + k0 + a_k + c);
            As[a_k+c+0][a_o] = v.x;
            As[a_k+c+1][a_o] = v.y;
            As[a_k+c+2][a_o] = v.z;
            As[a_k+c+3][a_o] = v.w;
        }
        // ---- stage B ----
        if constexpr (MODE == 2) {
            const int kabs = k0 + b_k;
            const float aa = a1p[kabs], cc = c1p[kabs], eb = se_ebp[kabs];
            float ew[SEC_];
            #pragma unroll
            for (int j = 0; j < SEC_; j++) ew[j] = se_ewp[kabs*SEC_ + j];
            #pragma unroll
            for (int c = 0; c < B_PER_T; c += 4) {
                const float4 h = *(const float4*)(Bb + (long)kabs*ldb + bn + b_n + c);
                float4 e = make_float4(eb, eb, eb, eb);
                #pragma unroll
                for (int j = 0; j < SEC_; j++) {
                    const float4 sv = *(const float4*)&sswl[j][b_n + c];
                    e.x += ew[j]*sv.x; e.y += ew[j]*sv.y;
                    e.z += ew[j]*sv.z; e.w += ew[j]*sv.w;
                }
                float4 o;
                o.x = (1.f/(1.f+__expf(-e.x))) * (aa*h.x + cc);
                o.y = (1.f/(1.f+__expf(-e.y))) * (aa*h.y + cc);
                o.z = (1.f/(1.f+__expf(-e.z))) * (aa*h.z + cc);
                o.w = (1.f/(1.f+__expf(-e.w))) * (aa*h.w + cc);
                *(float4*)&Bs[b_k][b_n + c] = o;
            }
        } else {
            #pragma unroll
            for (int c = 0; c < B_PER_T; c += 4) {
                const float4 v = *(const float4*)(Bb + (long)(k0 + b_k)*ldb + bn + b_n + c);
                *(float4*)&Bs[b_k][b_n + c] = v;
            }
        }
        __syncthreads();
        // ---- compute ----
        #pragma unroll
        for (int k = 0; k < BK; k++) {
            float av[TM], bv[TN];
            #pragma unroll
            for (int i = 0; i < TM; i += 4) *(float4*)&av[i] = *(const float4*)&As[k][ty*TM + i];
            #pragma unroll
            for (int j = 0; j < TN; j += 4) *(float4*)&bv[j] = *(const float4*)&Bs[k][tx*TN + j];
            #pragma unroll
            for (int i = 0; i < TM; i++)
                #pragma unroll
                for (int j = 0; j < TN; j++)
                    acc[i][j] += av[i]*bv[j];
        }
        __syncthreads();
    }

    // ---- epilogue ----
    float* Cb = C + (long)b * strideC;

    if constexpr (MODE == 1) {
        // add inverse-distance-weighted gather of G rows
        const float* Gb = Gp + (long)b * strideG;
        int ii0[TN], ii1[TN], ii2[TN];
        float ww0[TN], ww1[TN], ww2[TN];
        #pragma unroll
        for (int j = 0; j < TN; j++) {
            const long base = ((long)b*N_ + bn + tx*TN + j)*3;
            ii0[j] = idxp[base+0]; ii1[j] = idxp[base+1]; ii2[j] = idxp[base+2];
            ww0[j] = wgtp[base+0]; ww1[j] = wgtp[base+1]; ww2[j] = wgtp[base+2];
        }
        #pragma unroll
        for (int i = 0; i < TM; i++) {
            const float* Gr = Gb + (long)(bm + ty*TM + i)*M_;
            #pragma unroll
            for (int j = 0; j < TN; j++)
                acc[i][j] += ww0[j]*Gr[ii0[j]] + ww1[j]*Gr[ii1[j]] + ww2[j]*Gr[ii2[j]];
        }
    }

    float ssum[TM], ssq[TM];
    #pragma unroll
    for (int i = 0; i < TM; i++) { ssum[i] = 0.f; ssq[i] = 0.f; }

    #pragma unroll
    for (int i = 0; i < TM; i++) {
        float* row = Cb + (long)(bm + ty*TM + i)*ldc + bn + tx*TN;
        #pragma unroll
        for (int j = 0; j < TN; j += 4) {
            float4 v; v.x = acc[i][j]; v.y = acc[i][j+1]; v.z = acc[i][j+2]; v.w = acc[i][j+3];
            *(float4*)(row + j) = v;
        }
        if constexpr (MODE != 0) {
            #pragma unroll
            for (int j = 0; j < TN; j++) { const float v = acc[i][j]; ssum[i] += v; ssq[i] += v*v; }
        }
    }

    if constexpr (MODE != 0) {
        constexpr int TXN = BN/TN;
        float* red = (float*)As;   // BM*TXN floats fits in As
        __syncthreads();
        #pragma unroll
        for (int i = 0; i < TM; i++) red[(ty*TM + i)*TXN + tx] = ssum[i];
        __syncthreads();
        for (int r = tid; r < BM; r += THREADS) {
            float t = 0.f;
            for (int x = 0; x < TXN; x++) t += red[r*TXN + x];
            atomicAdd(&stats[bm + r], t);
        }
        __syncthreads();
        #pragma unroll
        for (int i = 0; i < TM; i++) red[(ty*TM + i)*TXN + tx] = ssq[i];
        __syncthreads();
        for (int r = tid; r < BM; r += THREADS) {
            float t = 0.f;
            for (int x = 0; x < TXN; x++) t += red[r*TXN + x];
            atomicAdd(&stats[H_ + bm + r], t);
        }
    }
}

// ---------------------------------------------------------------------------
// finalize1: BN1 params + fold into SE-reduce weights
// a1 = g1*rsqrt(var+eps); c1 = b1 - mean*a1
// rw2[j][o] = se_rw[j][o]*a1[o];  rbAdj[j] = se_rb[j] + sum_o se_rw[j][o]*c1[o]
// ---------------------------------------------------------------------------
__global__ __launch_bounds__(256)
void finalize1_kernel(const float* __restrict__ stats,
                      const float* __restrict__ g, const float* __restrict__ bb,
                      const float* __restrict__ se_rw, const float* __restrict__ se_rb,
                      float* __restrict__ a1, float* __restrict__ c1,
                      float* __restrict__ rw2, float* __restrict__ rbAdj)
{
    __shared__ float cbuf[H_];
    __shared__ float red[256];
    const int o = threadIdx.x;
    const float inv = 1.f / (float)(B_ * N_);
    const float S1 = stats[o], S2 = stats[H_ + o];
    const float mean = S1 * inv;
    const float var  = S2 * inv - mean*mean;
    const float a = g[o] * rsqrtf(var + BN_EPS);
    const float c = bb[o] - mean*a;
    a1[o] = a; c1[o] = c; cbuf[o] = c;
    for (int j = 0; j < SEC_; j++) rw2[j*H_ + o] = se_rw[j*H_ + o] * a;
    __syncthreads();
    for (int j = 0; j < SEC_; j++) {
        red[o] = se_rw[j*H_ + o] * cbuf[o];
        __syncthreads();
        for (int s = 128; s > 0; s >>= 1) {
            if (o < s) red[o] += red[o + s];
            __syncthreads();
        }
        if (o == 0) rbAdj[j] = se_rb[j] + red[0];
        __syncthreads();
    }
}

// ---------------------------------------------------------------------------
// SE reduce: spart[oc][b][j][n] = sum_{o in chunk oc} rw2[j][o] * h1[b][o][n]
// ---------------------------------------------------------------------------
__global__ __launch_bounds__(256)
void se_reduce_kernel(const float* __restrict__ h1, const float* __restrict__ rw2,
                      float* __restrict__ spart)
{
    __shared__ float rwl[SEC_][128];
    const int b = blockIdx.y, oc = blockIdx.z;
    const int n0 = blockIdx.x * 512 + threadIdx.x * 2;
    for (int i = threadIdx.x; i < SEC_*128; i += 256) {
        const int j = i / 128, o = i % 128;
        rwl[j][o] = rw2[j*H_ + oc*128 + o];
    }
    __syncthreads();
    float2 acc[SEC_];
    #pragma unroll
    for (int j = 0; j < SEC_; j++) { acc[j].x = 0.f; acc[j].y = 0.f; }
    const float* hp = h1 + ((long)b*H_ + oc*128)*N_ + n0;
    for (int o = 0; o < 128; o++) {
        const float2 h = *(const float2*)(hp + (long)o*N_);
        #pragma unroll
        for (int j = 0; j < SEC_; j++) {
            const float r = rwl[j][o];
            acc[j].x += r*h.x; acc[j].y += r*h.y;
        }
    }
    float* sp = spart + ((long)oc*B_ + b)*SEC_*N_ + n0;
    #pragma unroll
    for (int j = 0; j < SEC_; j++) *(float2*)(sp + (long)j*N_) = acc[j];
}

__global__ __launch_bounds__(256)
void finalize2_kernel(const float* __restrict__ stats,
                      const float* __restrict__ g, const float* __restrict__ bb,
                      float* __restrict__ a2, float* __restrict__ c2)
{
    const int o = threadIdx.x;
    const float inv = 1.f / (float)(B_ * N_);
    const float S1 = stats[o], S2 = stats[H_ + o];
    const float mean = S1 * inv;
    const float var  = S2 * inv - mean*mean;
    const float a = g[o] * rsqrtf(var + BN_EPS);
    a2[o] = a; c2[o] = bb[o] - mean*a;
}

// final in-place BN2 + ReLU on d_out
__global__ __launch_bounds__(256)
void bn_relu_kernel(float* __restrict__ out, const float* __restrict__ a2,
                    const float* __restrict__ c2)
{
    const long e = ((long)blockIdx.x * 256 + threadIdx.x) * 4;
    const int o = (int)((e / N_) % H_);
    float4 v = *(float4*)(out + e);
    const float a = a2[o], c = c2[o];
    v.x = fmaxf(a*v.x + c, 0.f);
    v.y = fmaxf(a*v.y + c, 0.f);
    v.z = fmaxf(a*v.z + c, 0.f);
    v.w = fmaxf(a*v.w + c, 0.f);
    *(float4*)(out + e) = v;
}

// ---------------------------------------------------------------------------
extern "C" void kernel_launch(void* const* d_in, const int* in_sizes, int n_in,
                              void* d_out, int out_size, void* d_ws, size_t ws_size,
                              hipStream_t stream)
{
    const float* unknown = (const float*)d_in[0];
    const float* known   = (const float*)d_in[1];
    const float* uf      = (const float*)d_in[2];
    const float* kf      = (const float*)d_in[3];
    const float* W1      = (const float*)d_in[4];
    const float* g1      = (const float*)d_in[5];
    const float* b1      = (const float*)d_in[6];
    const float* se_rw   = (const float*)d_in[7];
    const float* se_rb   = (const float*)d_in[8];
    const float* se_ew   = (const float*)d_in[9];
    const float* se_eb   = (const float*)d_in[10];
    const float* W2      = (const float*)d_in[11];
    const float* g2      = (const float*)d_in[12];
    const float* b2      = (const float*)d_in[13];

    char* ws = (char*)d_ws;
    size_t off = 0;
    auto alloc = [&](size_t bytes) -> void* {
        void* p = ws + off;
        off += (bytes + 255) & ~(size_t)255;
        return p;
    };
    int*   idxp   = (int*)  alloc((size_t)B_*N_*3*4);
    float* wgtp   = (float*)alloc((size_t)B_*N_*3*4);
    float* G      = (float*)alloc((size_t)B_*H_*M_*4);        // 16 MB
    float* h1     = (float*)alloc((size_t)B_*H_*N_*4);        // 64 MB
    float* spart  = (float*)alloc((size_t)2*B_*SEC_*N_*4);    // 5 MB
    float* stats1 = (float*)alloc(2*H_*4);
    float* stats2 = (float*)alloc(2*H_*4);
    float* a1     = (float*)alloc(H_*4);
    float* c1     = (float*)alloc(H_*4);
    float* rw2    = (float*)alloc(SEC_*H_*4);
    float* rbAdj  = (float*)alloc(64*4);
    float* a2     = (float*)alloc(H_*4);
    float* c2     = (float*)alloc(H_*4);
    (void)ws_size; (void)in_sizes; (void)n_in; (void)out_size;

    float* out = (float*)d_out;

    // zero BN stat accumulators (stats1 and stats2 are contiguous, 256B-padded)
    hipMemsetAsync(stats1, 0, 2 * ((2*H_*4 + 255) & ~(size_t)255), stream);

    // K1: three_nn
    three_nn_kernel<<<dim3(N_/256, B_), 256, 0, stream>>>(unknown, known, idxp, wgtp);

    // K2: G = W1[:, :512] @ kf   (per batch)   [256 x 1024], K=512
    gemm_f32<64,128,16,4,8,0><<<dim3(M_/128, H_/64, B_), 256, 0, stream>>>(
        W1, C1_+C2_, kf, (long)C2_*M_, M_, G, (long)H_*M_, M_, C2_,
        nullptr, 0, nullptr, nullptr, nullptr,
        nullptr, nullptr, nullptr, nullptr, nullptr, nullptr);

    // K3: h1 = W1[:, 512:] @ uf + gather(G)  + BN1 stats
    gemm_f32<128,128,16,8,8,1><<<dim3(N_/128, H_/128, B_), 256, 0, stream>>>(
        W1 + C2_, C1_+C2_, uf, (long)C1_*N_, N_, h1, (long)H_*N_, N_, C1_,
        G, (long)H_*M_, idxp, wgtp, stats1,
        nullptr, nullptr, nullptr, nullptr, nullptr, nullptr);

    // K4: BN1 finalize + SE weight folding
    finalize1_kernel<<<1, 256, 0, stream>>>(stats1, g1, b1, se_rw, se_rb, a1, c1, rw2, rbAdj);

    // K5: SE reduce partials over two o-chunks
    se_reduce_kernel<<<dim3(N_/512, B_, 2), 256, 0, stream>>>(h1, rw2, spart);

    // K6: conv2 with fused SE expand + sigmoid gate on staged B; writes pre-BN to d_out
    gemm_f32<128,128,16,8,8,2><<<dim3(N_/128, H_/128, B_), 256, 0, stream>>>(
        W2, H_, h1, (long)H_*N_, N_, out, (long)H_*N_, N_, H_,
        nullptr, 0, nullptr, nullptr, stats2,
        spart, rbAdj, se_ew, se_eb, a1, c1);

    // K7: BN2 finalize
    finalize2_kernel<<<1, 256, 0, stream>>>(stats2, g2, b2, a2, c2);

    // K8: in-place BN2 + ReLU
    bn_relu_kernel<<<dim3((unsigned)((long)B_*H_*N_/1024)), 256, 0, stream>>>(out, a2, c2);
}

// Round 2
// 681.011 us; speedup vs baseline: 1.1346x; 1.1346x over previous
//
#include <hip/hip_runtime.h>
#include <math.h>

#define B_ 16
#define N_ 4096
#define M_ 1024
#define C1_ 256
#define C2_ 512
#define H_ 256
#define SEC_ 10
#define OC_ 8
#define BN_EPS 1e-5f

typedef _Float16 f16;
typedef f16 f16x8 __attribute__((ext_vector_type(8)));
typedef f16 f16x4 __attribute__((ext_vector_type(4)));
typedef f16 f16x2 __attribute__((ext_vector_type(2)));
typedef float f32x4 __attribute__((ext_vector_type(4)));

// ---------------------------------------------------------------------------
// K1: three_nn
// ---------------------------------------------------------------------------
__global__ __launch_bounds__(256)
void three_nn_kernel(const float* __restrict__ unknown, const float* __restrict__ known,
                     int* __restrict__ idxp, float* __restrict__ wgtp)
{
    __shared__ float kx[M_], ky[M_], kz[M_];
    const int b = blockIdx.y;
    const float* kb = known + (long)b * M_ * 3;
    for (int i = threadIdx.x; i < M_; i += 256) {
        kx[i] = kb[i*3+0]; ky[i] = kb[i*3+1]; kz[i] = kb[i*3+2];
    }
    __syncthreads();
    const int n = blockIdx.x * 256 + threadIdx.x;
    const float* up = unknown + ((long)b * N_ + n) * 3;
    const float ux = up[0], uy = up[1], uz = up[2];
    float b0 = 1e30f, b1v = 1e30f, b2v = 1e30f;
    int j0 = 0, j1 = 0, j2 = 0;
    for (int m = 0; m < M_; m++) {
        const float dx = ux - kx[m], dy = uy - ky[m], dz = uz - kz[m];
        const float d = dx*dx + dy*dy + dz*dz;
        if (d < b2v) {
            if (d < b1v) {
                b2v = b1v; j2 = j1;
                if (d < b0) { b1v = b0; j1 = j0; b0 = d; j0 = m; }
                else        { b1v = d;  j1 = m; }
            } else { b2v = d; j2 = m; }
        }
    }
    const float r0 = 1.f/(b0 + 1e-8f), r1 = 1.f/(b1v + 1e-8f), r2 = 1.f/(b2v + 1e-8f);
    const float rs = 1.f/(r0 + r1 + r2);
    const long base = ((long)b * N_ + n) * 3;
    idxp[base+0] = j0; idxp[base+1] = j1; idxp[base+2] = j2;
    wgtp[base+0] = r0*rs; wgtp[base+1] = r1*rs; wgtp[base+2] = r2*rs;
}

// ---------------------------------------------------------------------------
// fp16-MFMA GEMM, BM=256 (full H) x BN=64, BK=64, 4 waves of 64x64.
// MODE 0: C fp32 store (G = W1a @ kf)
// MODE 1: += 3NN gather from G; store fp16 h1; BN1 stats
// MODE 2: B staged from fp16 h1 with SE gate; store fp16; BN2 stats
// A is row-major [256 x lda] fp32, k-contiguous -> no transpose needed.
// B (k x n, n-contig) transposed into Bs[n][k] during staging (half2 k-pairs).
// ---------------------------------------------------------------------------
template<int MODE>
__global__ __launch_bounds__(256)
void gemm_mfma(const float* __restrict__ A, int lda,
               const float* __restrict__ Bf, const f16* __restrict__ Bh,
               long strideB, int ldb, int K,
               float* __restrict__ Cf, f16* __restrict__ Ch, long strideC, int ldc,
               const float* __restrict__ Gp,
               const int* __restrict__ idxp, const float* __restrict__ wgtp,
               float* __restrict__ stats,
               const float* __restrict__ spart, const float* __restrict__ rbAdj,
               const float* __restrict__ se_ewp, const float* __restrict__ se_ebp,
               const float* __restrict__ a1p, const float* __restrict__ c1p)
{
    __shared__ __align__(16) f16 As[256*72];   // row stride 72 halves (pad 8)
    __shared__ __align__(16) f16 Bs[64*72];
    __shared__ float sswl[SEC_*64];

    const int b   = blockIdx.z;
    const int bn  = blockIdx.x * 64;
    const int tid = threadIdx.x;
    const int l = tid & 63, w = tid >> 6;
    const int lane16 = l & 15, quad = l >> 4;

    const float* Bfb = nullptr;
    const f16*   Bhb = nullptr;
    if constexpr (MODE == 2) Bhb = Bh + (long)b*strideB;
    else                     Bfb = Bf + (long)b*strideB;

    if constexpr (MODE == 2) {
        for (int i = tid; i < SEC_*64; i += 256) {
            const int j = i >> 6, nn = i & 63;
            float v = rbAdj[j];
            #pragma unroll
            for (int oc = 0; oc < OC_; oc++)
                v += spart[(((long)oc*B_ + b)*SEC_ + j)*N_ + bn + nn];
            sswl[j*64 + nn] = v / (1.f + __expf(-v));  // swish
        }
        __syncthreads();
    }

    f32x4 acc[4][4];
    #pragma unroll
    for (int i = 0; i < 4; i++)
        #pragma unroll
        for (int j = 0; j < 4; j++)
            acc[i][j] = (f32x4){0.f, 0.f, 0.f, 0.f};

    const int akb = (tid & 3) * 16;       // A k-block per thread
    const int arw = tid >> 2;             // A row (within 64-row pass)

    for (int k0 = 0; k0 < K; k0 += 64) {
        // ---- stage A: rows m, cols k0..k0+63, fp32 -> fp16 ----
        #pragma unroll
        for (int p = 0; p < 4; p++) {
            const int r = p*64 + arw;
            const float* src = A + (long)r*lda + k0 + akb;
            const float4 v0 = *(const float4*)(src);
            const float4 v1 = *(const float4*)(src + 4);
            const float4 v2 = *(const float4*)(src + 8);
            const float4 v3 = *(const float4*)(src + 12);
            f16x8 h0, h1;
            h0[0]=(f16)v0.x; h0[1]=(f16)v0.y; h0[2]=(f16)v0.z; h0[3]=(f16)v0.w;
            h0[4]=(f16)v1.x; h0[5]=(f16)v1.y; h0[6]=(f16)v1.z; h0[7]=(f16)v1.w;
            h1[0]=(f16)v2.x; h1[1]=(f16)v2.y; h1[2]=(f16)v2.z; h1[3]=(f16)v2.w;
            h1[4]=(f16)v3.x; h1[5]=(f16)v3.y; h1[6]=(f16)v3.z; h1[7]=(f16)v3.w;
            *(f16x8*)&As[r*72 + akb]     = h0;
            *(f16x8*)&As[r*72 + akb + 8] = h1;
        }
        // ---- stage B transposed: Bs[n][k], half2 over k-pairs ----
        #pragma unroll
        for (int it = 0; it < 2; it++) {
            const int slot = it*256 + tid;
            const int k2 = slot >> 4;           // k-pair 0..31
            const int n0 = (slot & 15) * 4;
            if constexpr (MODE == 2) {
                const int ka = k0 + 2*k2;
                const f16* s0 = Bhb + (long)ka*ldb + bn + n0;
                const f16x4 ua = *(const f16x4*)s0;
                const f16x4 ub = *(const f16x4*)(s0 + ldb);
                float val[2][4];
                #pragma unroll
                for (int r = 0; r < 2; r++) {
                    const int kr = ka + r;
                    const float aa = a1p[kr], cc = c1p[kr], eb = se_ebp[kr];
                    const float* ew = se_ewp + kr*SEC_;
                    #pragma unroll
                    for (int j = 0; j < 4; j++) {
                        float e = eb;
                        #pragma unroll
                        for (int q = 0; q < SEC_; q++) e += ew[q]*sswl[q*64 + n0 + j];
                        const float g  = 1.f/(1.f + __expf(-e));
                        const float hv = (r == 0) ? (float)ua[j] : (float)ub[j];
                        val[r][j] = g * (aa*hv + cc);
                    }
                }
                #pragma unroll
                for (int j = 0; j < 4; j++) {
                    f16x2 p; p[0] = (f16)val[0][j]; p[1] = (f16)val[1][j];
                    *(f16x2*)&Bs[(n0+j)*72 + 2*k2] = p;
                }
            } else {
                const float* s0 = Bfb + (long)(k0 + 2*k2)*ldb + bn + n0;
                const float4 u = *(const float4*)s0;
                const float4 v = *(const float4*)(s0 + ldb);
                f16x2 p0, p1, p2, p3;
                p0[0]=(f16)u.x; p0[1]=(f16)v.x;
                p1[0]=(f16)u.y; p1[1]=(f16)v.y;
                p2[0]=(f16)u.z; p2[1]=(f16)v.z;
                p3[0]=(f16)u.w; p3[1]=(f16)v.w;
                *(f16x2*)&Bs[(n0+0)*72 + 2*k2] = p0;
                *(f16x2*)&Bs[(n0+1)*72 + 2*k2] = p1;
                *(f16x2*)&Bs[(n0+2)*72 + 2*k2] = p2;
                *(f16x2*)&Bs[(n0+3)*72 + 2*k2] = p3;
            }
        }
        __syncthreads();
        // ---- MFMA: wave tile 64x64 = 4x4 of 16x16, two k32-steps ----
        const int abase = (w*64 + lane16)*72 + quad*8;
        const int bbase = lane16*72 + quad*8;
        #pragma unroll
        for (int s = 0; s < 2; s++) {
            f16x8 af[4], bf[4];
            #pragma unroll
            for (int i = 0; i < 4; i++) af[i] = *(const f16x8*)&As[abase + i*1152 + s*32];
            #pragma unroll
            for (int j = 0; j < 4; j++) bf[j] = *(const f16x8*)&Bs[bbase + j*1152 + s*32];
            #pragma unroll
            for (int i = 0; i < 4; i++)
                #pragma unroll
                for (int j = 0; j < 4; j++)
                    acc[i][j] = __builtin_amdgcn_mfma_f32_16x16x32_f16(af[i], bf[j], acc[i][j], 0, 0, 0);
        }
        __syncthreads();
    }

    // ---- epilogue ----
    if constexpr (MODE == 0) {
        float* Cb = Cf + (long)b*strideC;
        #pragma unroll
        for (int i = 0; i < 4; i++)
            #pragma unroll
            for (int r = 0; r < 4; r++) {
                const int row = w*64 + i*16 + quad*4 + r;
                float* rp = Cb + (long)row*ldc + bn + lane16;
                #pragma unroll
                for (int j = 0; j < 4; j++) rp[j*16] = acc[i][j][r];
            }
    } else {
        if constexpr (MODE == 1) {
            const float* Gb = Gp + (long)b*H_*M_;
            int ii[4][3]; float ww[4][3];
            #pragma unroll
            for (int j = 0; j < 4; j++) {
                const long base = ((long)b*N_ + bn + j*16 + lane16)*3;
                ii[j][0] = idxp[base+0]; ii[j][1] = idxp[base+1]; ii[j][2] = idxp[base+2];
                ww[j][0] = wgtp[base+0]; ww[j][1] = wgtp[base+1]; ww[j][2] = wgtp[base+2];
            }
            #pragma unroll
            for (int i = 0; i < 4; i++)
                #pragma unroll
                for (int r = 0; r < 4; r++) {
                    const int row = w*64 + i*16 + quad*4 + r;
                    const float* Gr = Gb + (long)row*M_;
                    #pragma unroll
                    for (int j = 0; j < 4; j++)
                        acc[i][j][r] += ww[j][0]*Gr[ii[j][0]] + ww[j][1]*Gr[ii[j][1]]
                                      + ww[j][2]*Gr[ii[j][2]];
                }
        }
        f16* Cb = Ch + (long)b*strideC;
        #pragma unroll
        for (int i = 0; i < 4; i++)
            #pragma unroll
            for (int r = 0; r < 4; r++) {
                const int row = w*64 + i*16 + quad*4 + r;
                float s1 = 0.f, s2 = 0.f;
                #pragma unroll
                for (int j = 0; j < 4; j++) {
                    const float v = acc[i][j][r];
                    s1 += v; s2 += v*v;
                    Cb[(long)row*ldc + bn + j*16 + lane16] = (f16)v;
                }
                #pragma unroll
                for (int off = 1; off < 16; off <<= 1) {
                    s1 += __shfl_xor(s1, off, 64);
                    s2 += __shfl_xor(s2, off, 64);
                }
                if (lane16 == 0) {
                    atomicAdd(&stats[row], s1);
                    atomicAdd(&stats[H_ + row], s2);
                }
            }
    }
}

// ---------------------------------------------------------------------------
__global__ __launch_bounds__(256)
void finalize1_kernel(const float* __restrict__ stats,
                      const float* __restrict__ g, const float* __restrict__ bb,
                      const float* __restrict__ se_rw, const float* __restrict__ se_rb,
                      float* __restrict__ a1, float* __restrict__ c1,
                      float* __restrict__ rw2, float* __restrict__ rbAdj)
{
    __shared__ float cbuf[H_];
    __shared__ float red[256];
    const int o = threadIdx.x;
    const float inv = 1.f / (float)(B_ * N_);
    const float S1 = stats[o], S2 = stats[H_ + o];
    const float mean = S1 * inv;
    const float var  = S2 * inv - mean*mean;
    const float a = g[o] * rsqrtf(var + BN_EPS);
    const float c = bb[o] - mean*a;
    a1[o] = a; c1[o] = c; cbuf[o] = c;
    for (int j = 0; j < SEC_; j++) rw2[j*H_ + o] = se_rw[j*H_ + o] * a;
    __syncthreads();
    for (int j = 0; j < SEC_; j++) {
        red[o] = se_rw[j*H_ + o] * cbuf[o];
        __syncthreads();
        for (int s = 128; s > 0; s >>= 1) {
            if (o < s) red[o] += red[o + s];
            __syncthreads();
        }
        if (o == 0) rbAdj[j] = se_rb[j] + red[0];
        __syncthreads();
    }
}

// ---------------------------------------------------------------------------
// SE reduce over OC_ chunks of H_/OC_ channels; h1 is fp16
// ---------------------------------------------------------------------------
__global__ __launch_bounds__(256)
void se_reduce_kernel(const f16* __restrict__ h1h, const float* __restrict__ rw2,
                      float* __restrict__ spart)
{
    constexpr int OCH = H_ / OC_;  // 32
    __shared__ float rwl[SEC_][OCH];
    const int b = blockIdx.y, oc = blockIdx.z;
    const int n0 = blockIdx.x*1024 + threadIdx.x*4;
    for (int i = threadIdx.x; i < SEC_*OCH; i += 256)
        rwl[i/OCH][i%OCH] = rw2[(i/OCH)*H_ + oc*OCH + (i%OCH)];
    __syncthreads();
    f32x4 acc[SEC_];
    #pragma unroll
    for (int j = 0; j < SEC_; j++) acc[j] = (f32x4){0.f,0.f,0.f,0.f};
    const f16* hp = h1h + ((long)b*H_ + oc*OCH)*N_ + n0;
    for (int o = 0; o < OCH; o++) {
        const f16x4 h = *(const f16x4*)(hp + (long)o*N_);
        f32x4 hf; hf[0]=(float)h[0]; hf[1]=(float)h[1]; hf[2]=(float)h[2]; hf[3]=(float)h[3];
        #pragma unroll
        for (int j = 0; j < SEC_; j++) acc[j] += rwl[j][o]*hf;
    }
    #pragma unroll
    for (int j = 0; j < SEC_; j++)
        *(f32x4*)&spart[(((long)oc*B_ + b)*SEC_ + j)*N_ + n0] = acc[j];
}

__global__ __launch_bounds__(256)
void finalize2_kernel(const float* __restrict__ stats,
                      const float* __restrict__ g, const float* __restrict__ bb,
                      float* __restrict__ a2, float* __restrict__ c2)
{
    const int o = threadIdx.x;
    const float inv = 1.f / (float)(B_ * N_);
    const float S1 = stats[o], S2 = stats[H_ + o];
    const float mean = S1 * inv;
    const float var  = S2 * inv - mean*mean;
    const float a = g[o] * rsqrtf(var + BN_EPS);
    a2[o] = a; c2[o] = bb[o] - mean*a;
}

// final: out = relu(a2*h2 + c2), h2 fp16 -> fp32 out
__global__ __launch_bounds__(256)
void bn_relu_kernel(const f16* __restrict__ h2h, float* __restrict__ out,
                    const float* __restrict__ a2, const float* __restrict__ c2)
{
    const long e = ((long)blockIdx.x*256 + threadIdx.x)*8;
    const int o = (int)((e >> 12) & (H_ - 1));
    const f16x8 v = *(const f16x8*)(h2h + e);
    const float a = a2[o], c = c2[o];
    float4 r0, r1;
    r0.x = fmaxf(a*(float)v[0] + c, 0.f);
    r0.y = fmaxf(a*(float)v[1] + c, 0.f);
    r0.z = fmaxf(a*(float)v[2] + c, 0.f);
    r0.w = fmaxf(a*(float)v[3] + c, 0.f);
    r1.x = fmaxf(a*(float)v[4] + c, 0.f);
    r1.y = fmaxf(a*(float)v[5] + c, 0.f);
    r1.z = fmaxf(a*(float)v[6] + c, 0.f);
    r1.w = fmaxf(a*(float)v[7] + c, 0.f);
    *(float4*)(out + e)     = r0;
    *(float4*)(out + e + 4) = r1;
}

// ---------------------------------------------------------------------------
extern "C" void kernel_launch(void* const* d_in, const int* in_sizes, int n_in,
                              void* d_out, int out_size, void* d_ws, size_t ws_size,
                              hipStream_t stream)
{
    const float* unknown = (const float*)d_in[0];
    const float* known   = (const float*)d_in[1];
    const float* uf      = (const float*)d_in[2];
    const float* kf      = (const float*)d_in[3];
    const float* W1      = (const float*)d_in[4];
    const float* g1      = (const float*)d_in[5];
    const float* b1      = (const float*)d_in[6];
    const float* se_rw   = (const float*)d_in[7];
    const float* se_rb   = (const float*)d_in[8];
    const float* se_ew   = (const float*)d_in[9];
    const float* se_eb   = (const float*)d_in[10];
    const float* W2      = (const float*)d_in[11];
    const float* g2      = (const float*)d_in[12];
    const float* b2      = (const float*)d_in[13];

    char* ws = (char*)d_ws;
    size_t off = 0;
    auto alloc = [&](size_t bytes) -> void* {
        void* p = ws + off;
        off += (bytes + 255) & ~(size_t)255;
        return p;
    };
    int*   idxp   = (int*)  alloc((size_t)B_*N_*3*4);
    float* wgtp   = (float*)alloc((size_t)B_*N_*3*4);
    float* G      = (float*)alloc((size_t)B_*H_*M_*4);          // 16.8 MB fp32
    f16*   h1h    = (f16*)  alloc((size_t)B_*H_*N_*2);          // 33.5 MB fp16
    f16*   h2h    = (f16*)  alloc((size_t)B_*H_*N_*2);          // 33.5 MB fp16
    float* spart  = (float*)alloc((size_t)OC_*B_*SEC_*N_*4);    // 21 MB
    float* stats1 = (float*)alloc(2*H_*4);
    float* stats2 = (float*)alloc(2*H_*4);
    float* a1     = (float*)alloc(H_*4);
    float* c1     = (float*)alloc(H_*4);
    float* rw2    = (float*)alloc(SEC_*H_*4);
    float* rbAdj  = (float*)alloc(64*4);
    float* a2     = (float*)alloc(H_*4);
    float* c2     = (float*)alloc(H_*4);
    (void)ws_size; (void)in_sizes; (void)n_in; (void)out_size;

    float* out = (float*)d_out;

    hipMemsetAsync(stats1, 0, 2*H_*4, stream);
    hipMemsetAsync(stats2, 0, 2*H_*4, stream);

    // K1: three_nn
    three_nn_kernel<<<dim3(N_/256, B_), 256, 0, stream>>>(unknown, known, idxp, wgtp);

    // K2: G = W1[:, :512] @ kf   [256 x 1024] per batch, K=512
    gemm_mfma<0><<<dim3(M_/64, 1, B_), 256, 0, stream>>>(
        W1, C1_+C2_, kf, nullptr, (long)C2_*M_, M_, C2_,
        G, nullptr, (long)H_*M_, M_,
        nullptr, nullptr, nullptr, nullptr,
        nullptr, nullptr, nullptr, nullptr, nullptr, nullptr);

    // K3: h1 = W1[:, 512:] @ uf + gather(G); fp16 store + BN1 stats
    gemm_mfma<1><<<dim3(N_/64, 1, B_), 256, 0, stream>>>(
        W1 + C2_, C1_+C2_, uf, nullptr, (long)C1_*N_, N_, C1_,
        nullptr, h1h, (long)H_*N_, N_,
        G, idxp, wgtp, stats1,
        nullptr, nullptr, nullptr, nullptr, nullptr, nullptr);

    // K4: BN1 finalize + SE fold
    finalize1_kernel<<<1, 256, 0, stream>>>(stats1, g1, b1, se_rw, se_rb, a1, c1, rw2, rbAdj);

    // K5: SE reduce partials
    se_reduce_kernel<<<dim3(N_/1024, B_, OC_), 256, 0, stream>>>(h1h, rw2, spart);

    // K6: conv2 with fused SE expand+sigmoid gate on staged B; fp16 store + BN2 stats
    gemm_mfma<2><<<dim3(N_/64, 1, B_), 256, 0, stream>>>(
        W2, H_, nullptr, h1h, (long)H_*N_, N_, H_,
        nullptr, h2h, (long)H_*N_, N_,
        nullptr, nullptr, nullptr, stats2,
        spart, rbAdj, se_ew, se_eb, a1, c1);

    // K7: BN2 finalize
    finalize2_kernel<<<1, 256, 0, stream>>>(stats2, g2, b2, a2, c2);

    // K8: out = relu(a2*h2 + c2)
    bn_relu_kernel<<<dim3((unsigned)((long)B_*H_*N_/2048)), 256, 0, stream>>>(h2h, out, a2, c2);
}

// Round 3
// 622.322 us; speedup vs baseline: 1.2416x; 1.0943x over previous
//
#include <hip/hip_runtime.h>
#include <math.h>

#define B_ 16
#define N_ 4096
#define M_ 1024
#define C1_ 256
#define C2_ 512
#define H_ 256
#define SEC_ 10
#define OC_ 8
#define BN_EPS 1e-5f

typedef _Float16 f16;
typedef f16 f16x8 __attribute__((ext_vector_type(8)));
typedef f16 f16x4 __attribute__((ext_vector_type(4)));
typedef f16 f16x2 __attribute__((ext_vector_type(2)));
typedef float f32x4 __attribute__((ext_vector_type(4)));

// ---------------------------------------------------------------------------
// K1: three_nn — known points read via wave-uniform loads (scalar cache),
// no LDS. Unrolled x4: 48 B = 3 aligned float4 per group.
// ---------------------------------------------------------------------------
__global__ __launch_bounds__(256)
void three_nn_kernel(const float* __restrict__ unknown, const float* __restrict__ known,
                     int* __restrict__ idxp, float* __restrict__ wgtp)
{
    const int b = blockIdx.y;
    const float* kb = known + (long)b * M_ * 3;
    const int n = blockIdx.x * 256 + threadIdx.x;
    const float* up = unknown + ((long)b * N_ + n) * 3;
    const float ux = up[0], uy = up[1], uz = up[2];
    float b0 = 1e30f, b1v = 1e30f, b2v = 1e30f;
    int j0 = 0, j1 = 0, j2 = 0;
    for (int m = 0; m < M_; m += 4) {
        const float4 q0 = *(const float4*)(kb + 3*m);
        const float4 q1 = *(const float4*)(kb + 3*m + 4);
        const float4 q2 = *(const float4*)(kb + 3*m + 8);
        const float px[4] = {q0.x, q0.w, q1.z, q2.y};
        const float py[4] = {q0.y, q1.x, q1.w, q2.z};
        const float pz[4] = {q0.z, q1.y, q2.x, q2.w};
        #pragma unroll
        for (int t = 0; t < 4; t++) {
            const float dx = ux - px[t], dy = uy - py[t], dz = uz - pz[t];
            const float d = dx*dx + dy*dy + dz*dz;
            if (d < b2v) {
                const int mm = m + t;
                if (d < b1v) {
                    b2v = b1v; j2 = j1;
                    if (d < b0) { b1v = b0; j1 = j0; b0 = d; j0 = mm; }
                    else        { b1v = d;  j1 = mm; }
                } else { b2v = d; j2 = mm; }
            }
        }
    }
    const float r0 = 1.f/(b0 + 1e-8f), r1 = 1.f/(b1v + 1e-8f), r2 = 1.f/(b2v + 1e-8f);
    const float rs = 1.f/(r0 + r1 + r2);
    const long base = ((long)b * N_ + n) * 3;
    idxp[base+0] = j0; idxp[base+1] = j1; idxp[base+2] = j2;
    wgtp[base+0] = r0*rs; wgtp[base+1] = r1*rs; wgtp[base+2] = r2*rs;
}

// ---------------------------------------------------------------------------
// fp16-MFMA GEMM, BM=256 (full H) x BN=64, BK=64, 4 waves of 64x64.
// MODE 0: C fp32 store (G = W1a @ kf)
// MODE 1: += 3NN gather from G; store fp16 h1; BN1 partial stats -> psum
// MODE 2: B staged from fp16 h1 with SE gate; store fp16; BN2 partials
// Stats: per-block partial sums (NO atomics — 524K same-line device atomics
// serialized ~200us in R2).
// ---------------------------------------------------------------------------
template<int MODE>
__global__ __launch_bounds__(256)
void gemm_mfma(const float* __restrict__ A, int lda,
               const float* __restrict__ Bf, const f16* __restrict__ Bh,
               long strideB, int ldb, int K,
               float* __restrict__ Cf, f16* __restrict__ Ch, long strideC, int ldc,
               const float* __restrict__ Gp,
               const int* __restrict__ idxp, const float* __restrict__ wgtp,
               float* __restrict__ psum,
               const float* __restrict__ spart, const float* __restrict__ rbAdj,
               const float* __restrict__ se_ewp, const float* __restrict__ se_ebp,
               const float* __restrict__ a1p, const float* __restrict__ c1p)
{
    __shared__ __align__(16) f16 As[256*72];   // row stride 72 halves (pad 8)
    __shared__ __align__(16) f16 Bs[64*72];
    __shared__ float sswl[SEC_*64];

    const int b   = blockIdx.z;
    const int bn  = blockIdx.x * 64;
    const int tid = threadIdx.x;
    const int l = tid & 63, w = tid >> 6;
    const int lane16 = l & 15, quad = l >> 4;

    const float* Bfb = nullptr;
    const f16*   Bhb = nullptr;
    if constexpr (MODE == 2) Bhb = Bh + (long)b*strideB;
    else                     Bfb = Bf + (long)b*strideB;

    if constexpr (MODE == 2) {
        for (int i = tid; i < SEC_*64; i += 256) {
            const int j = i >> 6, nn = i & 63;
            float v = rbAdj[j];
            #pragma unroll
            for (int oc = 0; oc < OC_; oc++)
                v += spart[(((long)oc*B_ + b)*SEC_ + j)*N_ + bn + nn];
            sswl[j*64 + nn] = v / (1.f + __expf(-v));  // swish
        }
        __syncthreads();
    }

    f32x4 acc[4][4];
    #pragma unroll
    for (int i = 0; i < 4; i++)
        #pragma unroll
        for (int j = 0; j < 4; j++)
            acc[i][j] = (f32x4){0.f, 0.f, 0.f, 0.f};

    const int akb = (tid & 3) * 16;       // A k-block per thread
    const int arw = tid >> 2;             // A row (within 64-row pass)

    for (int k0 = 0; k0 < K; k0 += 64) {
        // ---- stage A: rows m, cols k0..k0+63, fp32 -> fp16 ----
        #pragma unroll
        for (int p = 0; p < 4; p++) {
            const int r = p*64 + arw;
            const float* src = A + (long)r*lda + k0 + akb;
            const float4 v0 = *(const float4*)(src);
            const float4 v1 = *(const float4*)(src + 4);
            const float4 v2 = *(const float4*)(src + 8);
            const float4 v3 = *(const float4*)(src + 12);
            f16x8 h0, h1;
            h0[0]=(f16)v0.x; h0[1]=(f16)v0.y; h0[2]=(f16)v0.z; h0[3]=(f16)v0.w;
            h0[4]=(f16)v1.x; h0[5]=(f16)v1.y; h0[6]=(f16)v1.z; h0[7]=(f16)v1.w;
            h1[0]=(f16)v2.x; h1[1]=(f16)v2.y; h1[2]=(f16)v2.z; h1[3]=(f16)v2.w;
            h1[4]=(f16)v3.x; h1[5]=(f16)v3.y; h1[6]=(f16)v3.z; h1[7]=(f16)v3.w;
            *(f16x8*)&As[r*72 + akb]     = h0;
            *(f16x8*)&As[r*72 + akb + 8] = h1;
        }
        // ---- stage B transposed: Bs[n][k], half2 over k-pairs ----
        #pragma unroll
        for (int it = 0; it < 2; it++) {
            const int slot = it*256 + tid;
            const int k2 = slot >> 4;           // k-pair 0..31
            const int n0 = (slot & 15) * 4;
            if constexpr (MODE == 2) {
                const int ka = k0 + 2*k2;
                const f16* s0 = Bhb + (long)ka*ldb + bn + n0;
                const f16x4 ua = *(const f16x4*)s0;
                const f16x4 ub = *(const f16x4*)(s0 + ldb);
                float val[2][4];
                #pragma unroll
                for (int r = 0; r < 2; r++) {
                    const int kr = ka + r;
                    const float aa = a1p[kr], cc = c1p[kr], eb = se_ebp[kr];
                    const float* ew = se_ewp + kr*SEC_;
                    #pragma unroll
                    for (int j = 0; j < 4; j++) {
                        float e = eb;
                        #pragma unroll
                        for (int q = 0; q < SEC_; q++) e += ew[q]*sswl[q*64 + n0 + j];
                        const float g  = 1.f/(1.f + __expf(-e));
                        const float hv = (r == 0) ? (float)ua[j] : (float)ub[j];
                        val[r][j] = g * (aa*hv + cc);
                    }
                }
                #pragma unroll
                for (int j = 0; j < 4; j++) {
                    f16x2 p; p[0] = (f16)val[0][j]; p[1] = (f16)val[1][j];
                    *(f16x2*)&Bs[(n0+j)*72 + 2*k2] = p;
                }
            } else {
                const float* s0 = Bfb + (long)(k0 + 2*k2)*ldb + bn + n0;
                const float4 u = *(const float4*)s0;
                const float4 v = *(const float4*)(s0 + ldb);
                f16x2 p0, p1, p2, p3;
                p0[0]=(f16)u.x; p0[1]=(f16)v.x;
                p1[0]=(f16)u.y; p1[1]=(f16)v.y;
                p2[0]=(f16)u.z; p2[1]=(f16)v.z;
                p3[0]=(f16)u.w; p3[1]=(f16)v.w;
                *(f16x2*)&Bs[(n0+0)*72 + 2*k2] = p0;
                *(f16x2*)&Bs[(n0+1)*72 + 2*k2] = p1;
                *(f16x2*)&Bs[(n0+2)*72 + 2*k2] = p2;
                *(f16x2*)&Bs[(n0+3)*72 + 2*k2] = p3;
            }
        }
        __syncthreads();
        // ---- MFMA: wave tile 64x64 = 4x4 of 16x16, two k32-steps ----
        const int abase = (w*64 + lane16)*72 + quad*8;
        const int bbase = lane16*72 + quad*8;
        #pragma unroll
        for (int s = 0; s < 2; s++) {
            f16x8 af[4], bf[4];
            #pragma unroll
            for (int i = 0; i < 4; i++) af[i] = *(const f16x8*)&As[abase + i*1152 + s*32];
            #pragma unroll
            for (int j = 0; j < 4; j++) bf[j] = *(const f16x8*)&Bs[bbase + j*1152 + s*32];
            #pragma unroll
            for (int i = 0; i < 4; i++)
                #pragma unroll
                for (int j = 0; j < 4; j++)
                    acc[i][j] = __builtin_amdgcn_mfma_f32_16x16x32_f16(af[i], bf[j], acc[i][j], 0, 0, 0);
        }
        __syncthreads();
    }

    // ---- epilogue ----
    if constexpr (MODE == 0) {
        float* Cb = Cf + (long)b*strideC;
        #pragma unroll
        for (int i = 0; i < 4; i++)
            #pragma unroll
            for (int r = 0; r < 4; r++) {
                const int row = w*64 + i*16 + quad*4 + r;
                float* rp = Cb + (long)row*ldc + bn + lane16;
                #pragma unroll
                for (int j = 0; j < 4; j++) rp[j*16] = acc[i][j][r];
            }
    } else {
        if constexpr (MODE == 1) {
            const float* Gb = Gp + (long)b*H_*M_;
            int ii[4][3]; float ww[4][3];
            #pragma unroll
            for (int j = 0; j < 4; j++) {
                const long base = ((long)b*N_ + bn + j*16 + lane16)*3;
                ii[j][0] = idxp[base+0]; ii[j][1] = idxp[base+1]; ii[j][2] = idxp[base+2];
                ww[j][0] = wgtp[base+0]; ww[j][1] = wgtp[base+1]; ww[j][2] = wgtp[base+2];
            }
            #pragma unroll
            for (int i = 0; i < 4; i++)
                #pragma unroll
                for (int r = 0; r < 4; r++) {
                    const int row = w*64 + i*16 + quad*4 + r;
                    const float* Gr = Gb + (long)row*M_;
                    #pragma unroll
                    for (int j = 0; j < 4; j++)
                        acc[i][j][r] += ww[j][0]*Gr[ii[j][0]] + ww[j][1]*Gr[ii[j][1]]
                                      + ww[j][2]*Gr[ii[j][2]];
                }
        }
        const int bid = blockIdx.z * gridDim.x + blockIdx.x;
        float* ps = psum + (long)bid * (2*H_);
        f16* Cb = Ch + (long)b*strideC;
        #pragma unroll
        for (int i = 0; i < 4; i++)
            #pragma unroll
            for (int r = 0; r < 4; r++) {
                const int row = w*64 + i*16 + quad*4 + r;
                float s1 = 0.f, s2 = 0.f;
                #pragma unroll
                for (int j = 0; j < 4; j++) {
                    const float v = acc[i][j][r];
                    s1 += v; s2 += v*v;
                    Cb[(long)row*ldc + bn + j*16 + lane16] = (f16)v;
                }
                #pragma unroll
                for (int off = 1; off < 16; off <<= 1) {
                    s1 += __shfl_xor(s1, off, 64);
                    s2 += __shfl_xor(s2, off, 64);
                }
                if (lane16 == 0) {            // one lane per quad-row: plain stores
                    ps[row]      = s1;
                    ps[H_ + row] = s2;
                }
            }
    }
}

// ---------------------------------------------------------------------------
// reduce per-block partials -> stats[512]. grid 16 x 256 threads.
// ---------------------------------------------------------------------------
__global__ __launch_bounds__(256)
void reduce_stats_kernel(const float* __restrict__ psum, float* __restrict__ stats, int nblk)
{
    __shared__ float red[8][33];
    const int o  = blockIdx.x*32 + (threadIdx.x & 31);
    const int ch = threadIdx.x >> 5;
    float s = 0.f;
    for (int bid = ch; bid < nblk; bid += 8)
        s += psum[(long)bid*(2*H_) + o];
    red[ch][threadIdx.x & 31] = s;
    __syncthreads();
    if (ch == 0) {
        float t = 0.f;
        #pragma unroll
        for (int c = 0; c < 8; c++) t += red[c][threadIdx.x & 31];
        stats[o] = t;
    }
}

// ---------------------------------------------------------------------------
__global__ __launch_bounds__(256)
void finalize1_kernel(const float* __restrict__ stats,
                      const float* __restrict__ g, const float* __restrict__ bb,
                      const float* __restrict__ se_rw, const float* __restrict__ se_rb,
                      float* __restrict__ a1, float* __restrict__ c1,
                      float* __restrict__ rw2, float* __restrict__ rbAdj)
{
    __shared__ float cbuf[H_];
    __shared__ float red[256];
    const int o = threadIdx.x;
    const float inv = 1.f / (float)(B_ * N_);
    const float S1 = stats[o], S2 = stats[H_ + o];
    const float mean = S1 * inv;
    const float var  = S2 * inv - mean*mean;
    const float a = g[o] * rsqrtf(var + BN_EPS);
    const float c = bb[o] - mean*a;
    a1[o] = a; c1[o] = c; cbuf[o] = c;
    for (int j = 0; j < SEC_; j++) rw2[j*H_ + o] = se_rw[j*H_ + o] * a;
    __syncthreads();
    for (int j = 0; j < SEC_; j++) {
        red[o] = se_rw[j*H_ + o] * cbuf[o];
        __syncthreads();
        for (int s = 128; s > 0; s >>= 1) {
            if (o < s) red[o] += red[o + s];
            __syncthreads();
        }
        if (o == 0) rbAdj[j] = se_rb[j] + red[0];
        __syncthreads();
    }
}

// ---------------------------------------------------------------------------
// SE reduce over OC_ chunks of H_/OC_ channels; h1 is fp16
// ---------------------------------------------------------------------------
__global__ __launch_bounds__(256)
void se_reduce_kernel(const f16* __restrict__ h1h, const float* __restrict__ rw2,
                      float* __restrict__ spart)
{
    constexpr int OCH = H_ / OC_;  // 32
    __shared__ float rwl[SEC_][OCH];
    const int b = blockIdx.y, oc = blockIdx.z;
    const int n0 = blockIdx.x*1024 + threadIdx.x*4;
    for (int i = threadIdx.x; i < SEC_*OCH; i += 256)
        rwl[i/OCH][i%OCH] = rw2[(i/OCH)*H_ + oc*OCH + (i%OCH)];
    __syncthreads();
    f32x4 acc[SEC_];
    #pragma unroll
    for (int j = 0; j < SEC_; j++) acc[j] = (f32x4){0.f,0.f,0.f,0.f};
    const f16* hp = h1h + ((long)b*H_ + oc*OCH)*N_ + n0;
    for (int o = 0; o < OCH; o++) {
        const f16x4 h = *(const f16x4*)(hp + (long)o*N_);
        f32x4 hf; hf[0]=(float)h[0]; hf[1]=(float)h[1]; hf[2]=(float)h[2]; hf[3]=(float)h[3];
        #pragma unroll
        for (int j = 0; j < SEC_; j++) acc[j] += rwl[j][o]*hf;
    }
    #pragma unroll
    for (int j = 0; j < SEC_; j++)
        *(f32x4*)&spart[(((long)oc*B_ + b)*SEC_ + j)*N_ + n0] = acc[j];
}

__global__ __launch_bounds__(256)
void finalize2_kernel(const float* __restrict__ stats,
                      const float* __restrict__ g, const float* __restrict__ bb,
                      float* __restrict__ a2, float* __restrict__ c2)
{
    const int o = threadIdx.x;
    const float inv = 1.f / (float)(B_ * N_);
    const float S1 = stats[o], S2 = stats[H_ + o];
    const float mean = S1 * inv;
    const float var  = S2 * inv - mean*mean;
    const float a = g[o] * rsqrtf(var + BN_EPS);
    a2[o] = a; c2[o] = bb[o] - mean*a;
}

// final: out = relu(a2*h2 + c2), h2 fp16 -> fp32 out
__global__ __launch_bounds__(256)
void bn_relu_kernel(const f16* __restrict__ h2h, float* __restrict__ out,
                    const float* __restrict__ a2, const float* __restrict__ c2)
{
    const long e = ((long)blockIdx.x*256 + threadIdx.x)*8;
    const int o = (int)((e >> 12) & (H_ - 1));
    const f16x8 v = *(const f16x8*)(h2h + e);
    const float a = a2[o], c = c2[o];
    float4 r0, r1;
    r0.x = fmaxf(a*(float)v[0] + c, 0.f);
    r0.y = fmaxf(a*(float)v[1] + c, 0.f);
    r0.z = fmaxf(a*(float)v[2] + c, 0.f);
    r0.w = fmaxf(a*(float)v[3] + c, 0.f);
    r1.x = fmaxf(a*(float)v[4] + c, 0.f);
    r1.y = fmaxf(a*(float)v[5] + c, 0.f);
    r1.z = fmaxf(a*(float)v[6] + c, 0.f);
    r1.w = fmaxf(a*(float)v[7] + c, 0.f);
    *(float4*)(out + e)     = r0;
    *(float4*)(out + e + 4) = r1;
}

// ---------------------------------------------------------------------------
extern "C" void kernel_launch(void* const* d_in, const int* in_sizes, int n_in,
                              void* d_out, int out_size, void* d_ws, size_t ws_size,
                              hipStream_t stream)
{
    const float* unknown = (const float*)d_in[0];
    const float* known   = (const float*)d_in[1];
    const float* uf      = (const float*)d_in[2];
    const float* kf      = (const float*)d_in[3];
    const float* W1      = (const float*)d_in[4];
    const float* g1      = (const float*)d_in[5];
    const float* b1      = (const float*)d_in[6];
    const float* se_rw   = (const float*)d_in[7];
    const float* se_rb   = (const float*)d_in[8];
    const float* se_ew   = (const float*)d_in[9];
    const float* se_eb   = (const float*)d_in[10];
    const float* W2      = (const float*)d_in[11];
    const float* g2      = (const float*)d_in[12];
    const float* b2      = (const float*)d_in[13];

    char* ws = (char*)d_ws;
    size_t off = 0;
    auto alloc = [&](size_t bytes) -> void* {
        void* p = ws + off;
        off += (bytes + 255) & ~(size_t)255;
        return p;
    };
    const int NBLK = (N_/64) * B_;   // 1024 gemm blocks for MODE1/MODE2
    int*   idxp   = (int*)  alloc((size_t)B_*N_*3*4);
    float* wgtp   = (float*)alloc((size_t)B_*N_*3*4);
    float* G      = (float*)alloc((size_t)B_*H_*M_*4);          // 16.8 MB fp32
    f16*   h1h    = (f16*)  alloc((size_t)B_*H_*N_*2);          // 33.5 MB fp16
    f16*   h2h    = (f16*)  alloc((size_t)B_*H_*N_*2);          // 33.5 MB fp16
    float* spart  = (float*)alloc((size_t)OC_*B_*SEC_*N_*4);    // 21 MB
    float* psum1  = (float*)alloc((size_t)NBLK*2*H_*4);         // 2 MB
    float* psum2  = (float*)alloc((size_t)NBLK*2*H_*4);         // 2 MB
    float* stats1 = (float*)alloc(2*H_*4);
    float* stats2 = (float*)alloc(2*H_*4);
    float* a1     = (float*)alloc(H_*4);
    float* c1     = (float*)alloc(H_*4);
    float* rw2    = (float*)alloc(SEC_*H_*4);
    float* rbAdj  = (float*)alloc(64*4);
    float* a2     = (float*)alloc(H_*4);
    float* c2     = (float*)alloc(H_*4);
    (void)ws_size; (void)in_sizes; (void)n_in; (void)out_size;

    float* out = (float*)d_out;

    // K1: three_nn
    three_nn_kernel<<<dim3(N_/256, B_), 256, 0, stream>>>(unknown, known, idxp, wgtp);

    // K2: G = W1[:, :512] @ kf   [256 x 1024] per batch, K=512
    gemm_mfma<0><<<dim3(M_/64, 1, B_), 256, 0, stream>>>(
        W1, C1_+C2_, kf, nullptr, (long)C2_*M_, M_, C2_,
        G, nullptr, (long)H_*M_, M_,
        nullptr, nullptr, nullptr, nullptr,
        nullptr, nullptr, nullptr, nullptr, nullptr, nullptr);

    // K3: h1 = W1[:, 512:] @ uf + gather(G); fp16 store + BN1 partials
    gemm_mfma<1><<<dim3(N_/64, 1, B_), 256, 0, stream>>>(
        W1 + C2_, C1_+C2_, uf, nullptr, (long)C1_*N_, N_, C1_,
        nullptr, h1h, (long)H_*N_, N_,
        G, idxp, wgtp, psum1,
        nullptr, nullptr, nullptr, nullptr, nullptr, nullptr);

    // K3b: reduce partials -> stats1
    reduce_stats_kernel<<<dim3(16), 256, 0, stream>>>(psum1, stats1, NBLK);

    // K4: BN1 finalize + SE fold
    finalize1_kernel<<<1, 256, 0, stream>>>(stats1, g1, b1, se_rw, se_rb, a1, c1, rw2, rbAdj);

    // K5: SE reduce partials
    se_reduce_kernel<<<dim3(N_/1024, B_, OC_), 256, 0, stream>>>(h1h, rw2, spart);

    // K6: conv2 with fused SE expand+sigmoid gate on staged B; fp16 store + BN2 partials
    gemm_mfma<2><<<dim3(N_/64, 1, B_), 256, 0, stream>>>(
        W2, H_, nullptr, h1h, (long)H_*N_, N_, H_,
        nullptr, h2h, (long)H_*N_, N_,
        nullptr, nullptr, nullptr, psum2,
        spart, rbAdj, se_ew, se_eb, a1, c1);

    // K6b: reduce partials -> stats2
    reduce_stats_kernel<<<dim3(16), 256, 0, stream>>>(psum2, stats2, NBLK);

    // K7: BN2 finalize
    finalize2_kernel<<<1, 256, 0, stream>>>(stats2, g2, b2, a2, c2);

    // K8: out = relu(a2*h2 + c2)
    bn_relu_kernel<<<dim3((unsigned)((long)B_*H_*N_/2048)), 256, 0, stream>>>(h2h, out, a2, c2);
}

// Round 4
// 524.144 us; speedup vs baseline: 1.4742x; 1.1873x over previous
//
#include <hip/hip_runtime.h>
#include <math.h>

#define B_ 16
#define N_ 4096
#define M_ 1024
#define C1_ 256
#define C2_ 512
#define H_ 256
#define SEC_ 10
#define OC_ 8
#define BN_EPS 1e-5f

typedef _Float16 f16;
typedef f16 f16x8 __attribute__((ext_vector_type(8)));
typedef f16 f16x4 __attribute__((ext_vector_type(4)));
typedef f16 f16x2 __attribute__((ext_vector_type(2)));
typedef float f32x4 __attribute__((ext_vector_type(4)));

// ---------------------------------------------------------------------------
// K1: three_nn — wave-uniform scalar-cache reads of known points
// ---------------------------------------------------------------------------
__global__ __launch_bounds__(256)
void three_nn_kernel(const float* __restrict__ unknown, const float* __restrict__ known,
                     int* __restrict__ idxp, float* __restrict__ wgtp)
{
    const int b = blockIdx.y;
    const float* kb = known + (long)b * M_ * 3;
    const int n = blockIdx.x * 256 + threadIdx.x;
    const float* up = unknown + ((long)b * N_ + n) * 3;
    const float ux = up[0], uy = up[1], uz = up[2];
    float b0 = 1e30f, b1v = 1e30f, b2v = 1e30f;
    int j0 = 0, j1 = 0, j2 = 0;
    for (int m = 0; m < M_; m += 4) {
        const float4 q0 = *(const float4*)(kb + 3*m);
        const float4 q1 = *(const float4*)(kb + 3*m + 4);
        const float4 q2 = *(const float4*)(kb + 3*m + 8);
        const float px[4] = {q0.x, q0.w, q1.z, q2.y};
        const float py[4] = {q0.y, q1.x, q1.w, q2.z};
        const float pz[4] = {q0.z, q1.y, q2.x, q2.w};
        #pragma unroll
        for (int t = 0; t < 4; t++) {
            const float dx = ux - px[t], dy = uy - py[t], dz = uz - pz[t];
            const float d = dx*dx + dy*dy + dz*dz;
            if (d < b2v) {
                const int mm = m + t;
                if (d < b1v) {
                    b2v = b1v; j2 = j1;
                    if (d < b0) { b1v = b0; j1 = j0; b0 = d; j0 = mm; }
                    else        { b1v = d;  j1 = mm; }
                } else { b2v = d; j2 = mm; }
            }
        }
    }
    const float r0 = 1.f/(b0 + 1e-8f), r1 = 1.f/(b1v + 1e-8f), r2 = 1.f/(b2v + 1e-8f);
    const float rs = 1.f/(r0 + r1 + r2);
    const long base = ((long)b * N_ + n) * 3;
    idxp[base+0] = j0; idxp[base+1] = j1; idxp[base+2] = j2;
    wgtp[base+0] = r0*rs; wgtp[base+1] = r1*rs; wgtp[base+2] = r2*rs;
}

// ---------------------------------------------------------------------------
// fp16-MFMA GEMM, BM=256 (full H) x BN=64, BK=64, 4 waves of 64x64.
// MODE 0: store Gt[b][m][h] fp16 (transposed via LDS) — point-major G
// MODE 1: epilogue builds P[64pts][256h] in LDS from 3 contiguous Gt rows
//         per point (coalesced, L2-resident), acc += P; fp16 h1; psum stats
// MODE 2: B staged from fp16 h1 with SE gate; fp16 out; psum stats
// ---------------------------------------------------------------------------
template<int MODE>
__global__ __launch_bounds__(256)
void gemm_mfma(const float* __restrict__ A, int lda,
               const float* __restrict__ Bf, const f16* __restrict__ Bh,
               long strideB, int ldb, int K,
               f16* __restrict__ Ch, long strideC, int ldc,
               const f16* __restrict__ Gt,
               const int* __restrict__ idxp, const float* __restrict__ wgtp,
               float* __restrict__ psum,
               const float* __restrict__ spart, const float* __restrict__ rbAdj,
               const float* __restrict__ se_ewp, const float* __restrict__ se_ebp,
               const float* __restrict__ a1p, const float* __restrict__ c1p)
{
    __shared__ __align__(16) f16 As[256*72];   // row stride 72 halves (pad 8)
    __shared__ __align__(16) f16 Bs[64*72];
    __shared__ float sswl[SEC_*64];

    const int b   = blockIdx.z;
    const int bn  = blockIdx.x * 64;
    const int tid = threadIdx.x;
    const int l = tid & 63, w = tid >> 6;
    const int lane16 = l & 15, quad = l >> 4;

    const float* Bfb = nullptr;
    const f16*   Bhb = nullptr;
    if constexpr (MODE == 2) Bhb = Bh + (long)b*strideB;
    else                     Bfb = Bf + (long)b*strideB;

    if constexpr (MODE == 2) {
        for (int i = tid; i < SEC_*64; i += 256) {
            const int j = i >> 6, nn = i & 63;
            float v = rbAdj[j];
            #pragma unroll
            for (int oc = 0; oc < OC_; oc++)
                v += spart[(((long)oc*B_ + b)*SEC_ + j)*N_ + bn + nn];
            sswl[j*64 + nn] = v / (1.f + __expf(-v));  // swish
        }
        __syncthreads();
    }

    f32x4 acc[4][4];
    #pragma unroll
    for (int i = 0; i < 4; i++)
        #pragma unroll
        for (int j = 0; j < 4; j++)
            acc[i][j] = (f32x4){0.f, 0.f, 0.f, 0.f};

    const int akb = (tid & 3) * 16;       // A k-block per thread
    const int arw = tid >> 2;             // A row (within 64-row pass)

    for (int k0 = 0; k0 < K; k0 += 64) {
        // ---- stage A: rows m, cols k0..k0+63, fp32 -> fp16 ----
        #pragma unroll
        for (int p = 0; p < 4; p++) {
            const int r = p*64 + arw;
            const float* src = A + (long)r*lda + k0 + akb;
            const float4 v0 = *(const float4*)(src);
            const float4 v1 = *(const float4*)(src + 4);
            const float4 v2 = *(const float4*)(src + 8);
            const float4 v3 = *(const float4*)(src + 12);
            f16x8 h0, h1;
            h0[0]=(f16)v0.x; h0[1]=(f16)v0.y; h0[2]=(f16)v0.z; h0[3]=(f16)v0.w;
            h0[4]=(f16)v1.x; h0[5]=(f16)v1.y; h0[6]=(f16)v1.z; h0[7]=(f16)v1.w;
            h1[0]=(f16)v2.x; h1[1]=(f16)v2.y; h1[2]=(f16)v2.z; h1[3]=(f16)v2.w;
            h1[4]=(f16)v3.x; h1[5]=(f16)v3.y; h1[6]=(f16)v3.z; h1[7]=(f16)v3.w;
            *(f16x8*)&As[r*72 + akb]     = h0;
            *(f16x8*)&As[r*72 + akb + 8] = h1;
        }
        // ---- stage B transposed: Bs[n][k], half2 over k-pairs ----
        #pragma unroll
        for (int it = 0; it < 2; it++) {
            const int slot = it*256 + tid;
            const int k2 = slot >> 4;           // k-pair 0..31
            const int n0 = (slot & 15) * 4;
            if constexpr (MODE == 2) {
                const int ka = k0 + 2*k2;
                const f16* s0 = Bhb + (long)ka*ldb + bn + n0;
                const f16x4 ua = *(const f16x4*)s0;
                const f16x4 ub = *(const f16x4*)(s0 + ldb);
                float val[2][4];
                #pragma unroll
                for (int r = 0; r < 2; r++) {
                    const int kr = ka + r;
                    const float aa = a1p[kr], cc = c1p[kr], eb = se_ebp[kr];
                    const float* ew = se_ewp + kr*SEC_;
                    #pragma unroll
                    for (int j = 0; j < 4; j++) {
                        float e = eb;
                        #pragma unroll
                        for (int q = 0; q < SEC_; q++) e += ew[q]*sswl[q*64 + n0 + j];
                        const float g  = 1.f/(1.f + __expf(-e));
                        const float hv = (r == 0) ? (float)ua[j] : (float)ub[j];
                        val[r][j] = g * (aa*hv + cc);
                    }
                }
                #pragma unroll
                for (int j = 0; j < 4; j++) {
                    f16x2 p; p[0] = (f16)val[0][j]; p[1] = (f16)val[1][j];
                    *(f16x2*)&Bs[(n0+j)*72 + 2*k2] = p;
                }
            } else {
                const float* s0 = Bfb + (long)(k0 + 2*k2)*ldb + bn + n0;
                const float4 u = *(const float4*)s0;
                const float4 v = *(const float4*)(s0 + ldb);
                f16x2 p0, p1, p2, p3;
                p0[0]=(f16)u.x; p0[1]=(f16)v.x;
                p1[0]=(f16)u.y; p1[1]=(f16)v.y;
                p2[0]=(f16)u.z; p2[1]=(f16)v.z;
                p3[0]=(f16)u.w; p3[1]=(f16)v.w;
                *(f16x2*)&Bs[(n0+0)*72 + 2*k2] = p0;
                *(f16x2*)&Bs[(n0+1)*72 + 2*k2] = p1;
                *(f16x2*)&Bs[(n0+2)*72 + 2*k2] = p2;
                *(f16x2*)&Bs[(n0+3)*72 + 2*k2] = p3;
            }
        }
        __syncthreads();
        // ---- MFMA: wave tile 64x64 = 4x4 of 16x16, two k32-steps ----
        const int abase = (w*64 + lane16)*72 + quad*8;
        const int bbase = lane16*72 + quad*8;
        #pragma unroll
        for (int s = 0; s < 2; s++) {
            f16x8 af[4], bf[4];
            #pragma unroll
            for (int i = 0; i < 4; i++) af[i] = *(const f16x8*)&As[abase + i*1152 + s*32];
            #pragma unroll
            for (int j = 0; j < 4; j++) bf[j] = *(const f16x8*)&Bs[bbase + j*1152 + s*32];
            #pragma unroll
            for (int i = 0; i < 4; i++)
                #pragma unroll
                for (int j = 0; j < 4; j++)
                    acc[i][j] = __builtin_amdgcn_mfma_f32_16x16x32_f16(af[i], bf[j], acc[i][j], 0, 0, 0);
        }
        __syncthreads();
    }

    // ---- epilogue ----
    if constexpr (MODE == 0) {
        // transpose acc into LDS tile [64 m][264 h-stride], then coalesced Gt store
        f16* Gl = As;
        #pragma unroll
        for (int i = 0; i < 4; i++)
            #pragma unroll
            for (int r = 0; r < 4; r++) {
                const int h = w*64 + i*16 + quad*4 + r;
                #pragma unroll
                for (int j = 0; j < 4; j++)
                    Gl[(j*16 + lane16)*264 + h] = (f16)acc[i][j][r];
            }
        __syncthreads();
        f16* Gtb = Ch + (long)b*strideC + (long)bn*H_;
        #pragma unroll
        for (int it = 0; it < 8; it++) {
            const int t = it*256 + tid;
            const int m = t >> 5, c = (t & 31)*8;
            *(f16x8*)&Gtb[m*H_ + c] = *(const f16x8*)&Gl[m*264 + c];
        }
    } else {
        if constexpr (MODE == 1) {
            // build P[64 pts][256 h] in LDS from Gt rows (coalesced)
            f16* P = As;
            const int p  = tid >> 2;
            const int qd = tid & 3;
            const long ib = ((long)b*N_ + bn + p)*3;
            const int i0 = idxp[ib], i1 = idxp[ib+1], i2 = idxp[ib+2];
            const float w0 = wgtp[ib], w1 = wgtp[ib+1], w2 = wgtp[ib+2];
            const f16* gb = Gt + (long)b*M_*H_;
            const f16* g0 = gb + (long)i0*H_ + qd*64;
            const f16* g1 = gb + (long)i1*H_ + qd*64;
            const f16* g2 = gb + (long)i2*H_ + qd*64;
            f16* Pr = P + p*264 + qd*64;
            #pragma unroll
            for (int c = 0; c < 64; c += 8) {
                const f16x8 x0 = *(const f16x8*)&g0[c];
                const f16x8 x1 = *(const f16x8*)&g1[c];
                const f16x8 x2 = *(const f16x8*)&g2[c];
                f16x8 o;
                #pragma unroll
                for (int e = 0; e < 8; e++)
                    o[e] = (f16)(w0*(float)x0[e] + w1*(float)x1[e] + w2*(float)x2[e]);
                *(f16x8*)&Pr[c] = o;
            }
            __syncthreads();
            #pragma unroll
            for (int i = 0; i < 4; i++)
                #pragma unroll
                for (int r = 0; r < 4; r++) {
                    const int h = w*64 + i*16 + quad*4 + r;
                    #pragma unroll
                    for (int j = 0; j < 4; j++)
                        acc[i][j][r] += (float)P[(j*16 + lane16)*264 + h];
                }
        }
        const int bid = blockIdx.z * gridDim.x + blockIdx.x;
        float* ps = psum + (long)bid * (2*H_);
        f16* Cb = Ch + (long)b*strideC;
        #pragma unroll
        for (int i = 0; i < 4; i++)
            #pragma unroll
            for (int r = 0; r < 4; r++) {
                const int row = w*64 + i*16 + quad*4 + r;
                float s1 = 0.f, s2 = 0.f;
                #pragma unroll
                for (int j = 0; j < 4; j++) {
                    const float v = acc[i][j][r];
                    s1 += v; s2 += v*v;
                    Cb[(long)row*ldc + bn + j*16 + lane16] = (f16)v;
                }
                #pragma unroll
                for (int off = 1; off < 16; off <<= 1) {
                    s1 += __shfl_xor(s1, off, 64);
                    s2 += __shfl_xor(s2, off, 64);
                }
                if (lane16 == 0) {
                    ps[row]      = s1;
                    ps[H_ + row] = s2;
                }
            }
    }
}

// ---------------------------------------------------------------------------
__global__ __launch_bounds__(256)
void reduce_stats_kernel(const float* __restrict__ psum, float* __restrict__ stats, int nblk)
{
    __shared__ float red[8][33];
    const int o  = blockIdx.x*32 + (threadIdx.x & 31);
    const int ch = threadIdx.x >> 5;
    float s = 0.f;
    for (int bid = ch; bid < nblk; bid += 8)
        s += psum[(long)bid*(2*H_) + o];
    red[ch][threadIdx.x & 31] = s;
    __syncthreads();
    if (ch == 0) {
        float t = 0.f;
        #pragma unroll
        for (int c = 0; c < 8; c++) t += red[c][threadIdx.x & 31];
        stats[o] = t;
    }
}

// ---------------------------------------------------------------------------
__global__ __launch_bounds__(256)
void finalize1_kernel(const float* __restrict__ stats,
                      const float* __restrict__ g, const float* __restrict__ bb,
                      const float* __restrict__ se_rw, const float* __restrict__ se_rb,
                      float* __restrict__ a1, float* __restrict__ c1,
                      float* __restrict__ rw2, float* __restrict__ rbAdj)
{
    __shared__ float cbuf[H_];
    __shared__ float red[256];
    const int o = threadIdx.x;
    const float inv = 1.f / (float)(B_ * N_);
    const float S1 = stats[o], S2 = stats[H_ + o];
    const float mean = S1 * inv;
    const float var  = S2 * inv - mean*mean;
    const float a = g[o] * rsqrtf(var + BN_EPS);
    const float c = bb[o] - mean*a;
    a1[o] = a; c1[o] = c; cbuf[o] = c;
    for (int j = 0; j < SEC_; j++) rw2[j*H_ + o] = se_rw[j*H_ + o] * a;
    __syncthreads();
    for (int j = 0; j < SEC_; j++) {
        red[o] = se_rw[j*H_ + o] * cbuf[o];
        __syncthreads();
        for (int s = 128; s > 0; s >>= 1) {
            if (o < s) red[o] += red[o + s];
            __syncthreads();
        }
        if (o == 0) rbAdj[j] = se_rb[j] + red[0];
        __syncthreads();
    }
}

// ---------------------------------------------------------------------------
__global__ __launch_bounds__(256)
void se_reduce_kernel(const f16* __restrict__ h1h, const float* __restrict__ rw2,
                      float* __restrict__ spart)
{
    constexpr int OCH = H_ / OC_;  // 32
    __shared__ float rwl[SEC_][OCH];
    const int b = blockIdx.y, oc = blockIdx.z;
    const int n0 = blockIdx.x*1024 + threadIdx.x*4;
    for (int i = threadIdx.x; i < SEC_*OCH; i += 256)
        rwl[i/OCH][i%OCH] = rw2[(i/OCH)*H_ + oc*OCH + (i%OCH)];
    __syncthreads();
    f32x4 acc[SEC_];
    #pragma unroll
    for (int j = 0; j < SEC_; j++) acc[j] = (f32x4){0.f,0.f,0.f,0.f};
    const f16* hp = h1h + ((long)b*H_ + oc*OCH)*N_ + n0;
    for (int o = 0; o < OCH; o++) {
        const f16x4 h = *(const f16x4*)(hp + (long)o*N_);
        f32x4 hf; hf[0]=(float)h[0]; hf[1]=(float)h[1]; hf[2]=(float)h[2]; hf[3]=(float)h[3];
        #pragma unroll
        for (int j = 0; j < SEC_; j++) acc[j] += rwl[j][o]*hf;
    }
    #pragma unroll
    for (int j = 0; j < SEC_; j++)
        *(f32x4*)&spart[(((long)oc*B_ + b)*SEC_ + j)*N_ + n0] = acc[j];
}

__global__ __launch_bounds__(256)
void finalize2_kernel(const float* __restrict__ stats,
                      const float* __restrict__ g, const float* __restrict__ bb,
                      float* __restrict__ a2, float* __restrict__ c2)
{
    const int o = threadIdx.x;
    const float inv = 1.f / (float)(B_ * N_);
    const float S1 = stats[o], S2 = stats[H_ + o];
    const float mean = S1 * inv;
    const float var  = S2 * inv - mean*mean;
    const float a = g[o] * rsqrtf(var + BN_EPS);
    a2[o] = a; c2[o] = bb[o] - mean*a;
}

__global__ __launch_bounds__(256)
void bn_relu_kernel(const f16* __restrict__ h2h, float* __restrict__ out,
                    const float* __restrict__ a2, const float* __restrict__ c2)
{
    const long e = ((long)blockIdx.x*256 + threadIdx.x)*8;
    const int o = (int)((e >> 12) & (H_ - 1));
    const f16x8 v = *(const f16x8*)(h2h + e);
    const float a = a2[o], c = c2[o];
    float4 r0, r1;
    r0.x = fmaxf(a*(float)v[0] + c, 0.f);
    r0.y = fmaxf(a*(float)v[1] + c, 0.f);
    r0.z = fmaxf(a*(float)v[2] + c, 0.f);
    r0.w = fmaxf(a*(float)v[3] + c, 0.f);
    r1.x = fmaxf(a*(float)v[4] + c, 0.f);
    r1.y = fmaxf(a*(float)v[5] + c, 0.f);
    r1.z = fmaxf(a*(float)v[6] + c, 0.f);
    r1.w = fmaxf(a*(float)v[7] + c, 0.f);
    *(float4*)(out + e)     = r0;
    *(float4*)(out + e + 4) = r1;
}

// ---------------------------------------------------------------------------
extern "C" void kernel_launch(void* const* d_in, const int* in_sizes, int n_in,
                              void* d_out, int out_size, void* d_ws, size_t ws_size,
                              hipStream_t stream)
{
    const float* unknown = (const float*)d_in[0];
    const float* known   = (const float*)d_in[1];
    const float* uf      = (const float*)d_in[2];
    const float* kf      = (const float*)d_in[3];
    const float* W1      = (const float*)d_in[4];
    const float* g1      = (const float*)d_in[5];
    const float* b1      = (const float*)d_in[6];
    const float* se_rw   = (const float*)d_in[7];
    const float* se_rb   = (const float*)d_in[8];
    const float* se_ew   = (const float*)d_in[9];
    const float* se_eb   = (const float*)d_in[10];
    const float* W2      = (const float*)d_in[11];
    const float* g2      = (const float*)d_in[12];
    const float* b2      = (const float*)d_in[13];

    char* ws = (char*)d_ws;
    size_t off = 0;
    auto alloc = [&](size_t bytes) -> void* {
        void* p = ws + off;
        off += (bytes + 255) & ~(size_t)255;
        return p;
    };
    const int NBLK = (N_/64) * B_;   // 1024 gemm blocks for MODE1/MODE2
    int*   idxp   = (int*)  alloc((size_t)B_*N_*3*4);
    float* wgtp   = (float*)alloc((size_t)B_*N_*3*4);
    f16*   Gt     = (f16*)  alloc((size_t)B_*M_*H_*2);          // 8.4 MB fp16, [b][m][h]
    f16*   h1h    = (f16*)  alloc((size_t)B_*H_*N_*2);          // 33.5 MB fp16
    f16*   h2h    = (f16*)  alloc((size_t)B_*H_*N_*2);          // 33.5 MB fp16
    float* spart  = (float*)alloc((size_t)OC_*B_*SEC_*N_*4);    // 21 MB
    float* psum1  = (float*)alloc((size_t)NBLK*2*H_*4);         // 2 MB
    float* psum2  = (float*)alloc((size_t)NBLK*2*H_*4);         // 2 MB
    float* stats1 = (float*)alloc(2*H_*4);
    float* stats2 = (float*)alloc(2*H_*4);
    float* a1     = (float*)alloc(H_*4);
    float* c1     = (float*)alloc(H_*4);
    float* rw2    = (float*)alloc(SEC_*H_*4);
    float* rbAdj  = (float*)alloc(64*4);
    float* a2     = (float*)alloc(H_*4);
    float* c2     = (float*)alloc(H_*4);
    (void)ws_size; (void)in_sizes; (void)n_in; (void)out_size;

    float* out = (float*)d_out;

    // K1: three_nn
    three_nn_kernel<<<dim3(N_/256, B_), 256, 0, stream>>>(unknown, known, idxp, wgtp);

    // K2: Gt[b][m][h] = (W1[:, :512] @ kf)^T, fp16
    gemm_mfma<0><<<dim3(M_/64, 1, B_), 256, 0, stream>>>(
        W1, C1_+C2_, kf, nullptr, (long)C2_*M_, M_, C2_,
        Gt, (long)M_*H_, 0,
        nullptr, nullptr, nullptr, nullptr,
        nullptr, nullptr, nullptr, nullptr, nullptr, nullptr);

    // K3: h1 = W1[:, 512:] @ uf + interp(Gt); fp16 store + BN1 partials
    gemm_mfma<1><<<dim3(N_/64, 1, B_), 256, 0, stream>>>(
        W1 + C2_, C1_+C2_, uf, nullptr, (long)C1_*N_, N_, C1_,
        h1h, (long)H_*N_, N_,
        Gt, idxp, wgtp, psum1,
        nullptr, nullptr, nullptr, nullptr, nullptr, nullptr);

    // K3b: reduce partials -> stats1
    reduce_stats_kernel<<<dim3(16), 256, 0, stream>>>(psum1, stats1, NBLK);

    // K4: BN1 finalize + SE fold
    finalize1_kernel<<<1, 256, 0, stream>>>(stats1, g1, b1, se_rw, se_rb, a1, c1, rw2, rbAdj);

    // K5: SE reduce partials
    se_reduce_kernel<<<dim3(N_/1024, B_, OC_), 256, 0, stream>>>(h1h, rw2, spart);

    // K6: conv2 with fused SE expand+sigmoid gate; fp16 store + BN2 partials
    gemm_mfma<2><<<dim3(N_/64, 1, B_), 256, 0, stream>>>(
        W2, H_, nullptr, h1h, (long)H_*N_, N_, H_,
        h2h, (long)H_*N_, N_,
        nullptr, nullptr, nullptr, psum2,
        spart, rbAdj, se_ew, se_eb, a1, c1);

    // K6b: reduce partials -> stats2
    reduce_stats_kernel<<<dim3(16), 256, 0, stream>>>(psum2, stats2, NBLK);

    // K7: BN2 finalize
    finalize2_kernel<<<1, 256, 0, stream>>>(stats2, g2, b2, a2, c2);

    // K8: out = relu(a2*h2 + c2)
    bn_relu_kernel<<<dim3((unsigned)((long)B_*H_*N_/2048)), 256, 0, stream>>>(h2h, out, a2, c2);
}

// Round 6
// 446.416 us; speedup vs baseline: 1.7309x; 1.1741x over previous
//
#include <hip/hip_runtime.h>
#include <math.h>

#define B_ 16
#define N_ 4096
#define M_ 1024
#define C1_ 256
#define C2_ 512
#define H_ 256
#define SEC_ 10
#define OC_ 8
#define BN_EPS 1e-5f

typedef _Float16 f16;
typedef f16 f16x8 __attribute__((ext_vector_type(8)));
typedef f16 f16x4 __attribute__((ext_vector_type(4)));
typedef f16 f16x2 __attribute__((ext_vector_type(2)));
typedef float f32x4 __attribute__((ext_vector_type(4)));

// ---------------------------------------------------------------------------
// K1: three_nn v4 — occupancy structure of v3 (64 queries/block, 4-way wave
// m-split, LDS SoA) but EXACT (d, idx) ordering: strict-less insert scanning
// ascending m reproduces top_k's lowest-index tie-break bit-exactly.
// (v3's mantissa-truncation packing created artificial ties -> wrong
// neighbor picks -> absmax 1.15. Exact keys only.)
// ---------------------------------------------------------------------------
__global__ __launch_bounds__(256)
void three_nn_kernel(const float* __restrict__ unknown, const float* __restrict__ known,
                     int* __restrict__ idxp, float* __restrict__ wgtp)
{
    __shared__ float kx[M_], ky[M_], kz[M_];        // 12 KB SoA
    __shared__ float cd[4][64][3];                  // per-wave top-3 distances
    __shared__ int   ci[4][64][3];                  // per-wave top-3 indices
    const int b  = blockIdx.y;
    const int bn = blockIdx.x * 64;
    const int t  = threadIdx.x;
    const float* kb = known + (long)b * M_ * 3;

    // stage 1024 points AoS->SoA: thread t handles points 4t..4t+3
    {
        const float4 q0 = *(const float4*)(kb + 12*t);
        const float4 q1 = *(const float4*)(kb + 12*t + 4);
        const float4 q2 = *(const float4*)(kb + 12*t + 8);
        const int m = 4*t;
        kx[m+0]=q0.x; ky[m+0]=q0.y; kz[m+0]=q0.z;
        kx[m+1]=q0.w; ky[m+1]=q1.x; kz[m+1]=q1.y;
        kx[m+2]=q1.z; ky[m+2]=q1.w; kz[m+2]=q2.x;
        kx[m+3]=q2.y; ky[m+3]=q2.z; kz[m+3]=q2.w;
    }
    __syncthreads();

    const int w = t >> 6, ln = t & 63;
    const int n = bn + ln;
    const float* up = unknown + ((long)b * N_ + n) * 3;
    const float ux = up[0], uy = up[1], uz = up[2];

    float b0 = 1e30f, b1v = 1e30f, b2v = 1e30f;
    int j0 = 0, j1 = 0, j2 = 0;

    const int m0 = w * 256;
    for (int m = m0; m < m0 + 256; m += 4) {
        const float4 X = *(const float4*)&kx[m];
        const float4 Y = *(const float4*)&ky[m];
        const float4 Z = *(const float4*)&kz[m];
        const float px[4] = {X.x, X.y, X.z, X.w};
        const float py[4] = {Y.x, Y.y, Y.z, Y.w};
        const float pz[4] = {Z.x, Z.y, Z.z, Z.w};
        #pragma unroll
        for (int q = 0; q < 4; q++) {
            const float dx = ux - px[q], dy = uy - py[q], dz = uz - pz[q];
            const float d = dx*dx + dy*dy + dz*dz;
            if (d < b2v) {
                const int mm = m + q;
                if (d < b1v) {
                    b2v = b1v; j2 = j1;
                    if (d < b0) { b1v = b0; j1 = j0; b0 = d; j0 = mm; }
                    else        { b1v = d;  j1 = mm; }
                } else { b2v = d; j2 = mm; }
            }
        }
    }
    cd[w][ln][0] = b0;  cd[w][ln][1] = b1v; cd[w][ln][2] = b2v;
    ci[w][ln][0] = j0;  ci[w][ln][1] = j1;  ci[w][ln][2] = j2;
    __syncthreads();

    if (t < 64) {
        // merge in ascending chunk order; strict-less insert keeps lowest m on ties
        float d0 = cd[0][t][0], d1 = cd[0][t][1], d2 = cd[0][t][2];
        int   i0 = ci[0][t][0], i1 = ci[0][t][1], i2 = ci[0][t][2];
        #pragma unroll
        for (int c = 1; c < 4; c++) {
            #pragma unroll
            for (int j = 0; j < 3; j++) {
                const float d = cd[c][t][j];
                const int  ix = ci[c][t][j];
                if (d < d2) {
                    if (d < d1) {
                        d2 = d1; i2 = i1;
                        if (d < d0) { d1 = d0; i1 = i0; d0 = d; i0 = ix; }
                        else        { d1 = d;  i1 = ix; }
                    } else { d2 = d; i2 = ix; }
                }
            }
        }
        const float r0 = 1.f/(d0 + 1e-8f), r1 = 1.f/(d1 + 1e-8f), r2 = 1.f/(d2 + 1e-8f);
        const float rs = 1.f/(r0 + r1 + r2);
        const long base = ((long)b * N_ + bn + t) * 3;
        idxp[base+0] = i0; idxp[base+1] = i1; idxp[base+2] = i2;
        wgtp[base+0] = r0*rs; wgtp[base+1] = r1*rs; wgtp[base+2] = r2*rs;
    }
}

// ---------------------------------------------------------------------------
// fp16-MFMA GEMM, BM=256 (full H) x BN=64, BK=64, 4 waves of 64x64.
// MODE 0: store Gt[b][m][h] fp16 (transposed via LDS) — point-major G
// MODE 1: epilogue builds P[64pts][256h] in LDS from 3 contiguous Gt rows
//         per point (coalesced, L2-resident), acc += P; fp16 h1; psum stats
// MODE 2: B staged from fp16 h1 with SE gate; fp16 out; psum stats
// ---------------------------------------------------------------------------
template<int MODE>
__global__ __launch_bounds__(256)
void gemm_mfma(const float* __restrict__ A, int lda,
               const float* __restrict__ Bf, const f16* __restrict__ Bh,
               long strideB, int ldb, int K,
               f16* __restrict__ Ch, long strideC, int ldc,
               const f16* __restrict__ Gt,
               const int* __restrict__ idxp, const float* __restrict__ wgtp,
               float* __restrict__ psum,
               const float* __restrict__ spart, const float* __restrict__ rbAdj,
               const float* __restrict__ se_ewp, const float* __restrict__ se_ebp,
               const float* __restrict__ a1p, const float* __restrict__ c1p)
{
    __shared__ __align__(16) f16 As[256*72];   // row stride 72 halves (pad 8)
    __shared__ __align__(16) f16 Bs[64*72];
    __shared__ float sswl[SEC_*64];

    const int b   = blockIdx.z;
    const int bn  = blockIdx.x * 64;
    const int tid = threadIdx.x;
    const int l = tid & 63, w = tid >> 6;
    const int lane16 = l & 15, quad = l >> 4;

    const float* Bfb = nullptr;
    const f16*   Bhb = nullptr;
    if constexpr (MODE == 2) Bhb = Bh + (long)b*strideB;
    else                     Bfb = Bf + (long)b*strideB;

    if constexpr (MODE == 2) {
        for (int i = tid; i < SEC_*64; i += 256) {
            const int j = i >> 6, nn = i & 63;
            float v = rbAdj[j];
            #pragma unroll
            for (int oc = 0; oc < OC_; oc++)
                v += spart[(((long)oc*B_ + b)*SEC_ + j)*N_ + bn + nn];
            sswl[j*64 + nn] = v / (1.f + __expf(-v));  // swish
        }
        __syncthreads();
    }

    f32x4 acc[4][4];
    #pragma unroll
    for (int i = 0; i < 4; i++)
        #pragma unroll
        for (int j = 0; j < 4; j++)
            acc[i][j] = (f32x4){0.f, 0.f, 0.f, 0.f};

    const int akb = (tid & 3) * 16;       // A k-block per thread
    const int arw = tid >> 2;             // A row (within 64-row pass)

    for (int k0 = 0; k0 < K; k0 += 64) {
        // ---- stage A: rows m, cols k0..k0+63, fp32 -> fp16 ----
        #pragma unroll
        for (int p = 0; p < 4; p++) {
            const int r = p*64 + arw;
            const float* src = A + (long)r*lda + k0 + akb;
            const float4 v0 = *(const float4*)(src);
            const float4 v1 = *(const float4*)(src + 4);
            const float4 v2 = *(const float4*)(src + 8);
            const float4 v3 = *(const float4*)(src + 12);
            f16x8 h0, h1;
            h0[0]=(f16)v0.x; h0[1]=(f16)v0.y; h0[2]=(f16)v0.z; h0[3]=(f16)v0.w;
            h0[4]=(f16)v1.x; h0[5]=(f16)v1.y; h0[6]=(f16)v1.z; h0[7]=(f16)v1.w;
            h1[0]=(f16)v2.x; h1[1]=(f16)v2.y; h1[2]=(f16)v2.z; h1[3]=(f16)v2.w;
            h1[4]=(f16)v3.x; h1[5]=(f16)v3.y; h1[6]=(f16)v3.z; h1[7]=(f16)v3.w;
            *(f16x8*)&As[r*72 + akb]     = h0;
            *(f16x8*)&As[r*72 + akb + 8] = h1;
        }
        // ---- stage B transposed: Bs[n][k], half2 over k-pairs ----
        #pragma unroll
        for (int it = 0; it < 2; it++) {
            const int slot = it*256 + tid;
            const int k2 = slot >> 4;           // k-pair 0..31
            const int n0 = (slot & 15) * 4;
            if constexpr (MODE == 2) {
                const int ka = k0 + 2*k2;
                const f16* s0 = Bhb + (long)ka*ldb + bn + n0;
                const f16x4 ua = *(const f16x4*)s0;
                const f16x4 ub = *(const f16x4*)(s0 + ldb);
                float val[2][4];
                #pragma unroll
                for (int r = 0; r < 2; r++) {
                    const int kr = ka + r;
                    const float aa = a1p[kr], cc = c1p[kr], eb = se_ebp[kr];
                    const float* ew = se_ewp + kr*SEC_;
                    #pragma unroll
                    for (int j = 0; j < 4; j++) {
                        float e = eb;
                        #pragma unroll
                        for (int q = 0; q < SEC_; q++) e += ew[q]*sswl[q*64 + n0 + j];
                        const float g  = 1.f/(1.f + __expf(-e));
                        const float hv = (r == 0) ? (float)ua[j] : (float)ub[j];
                        val[r][j] = g * (aa*hv + cc);
                    }
                }
                #pragma unroll
                for (int j = 0; j < 4; j++) {
                    f16x2 p; p[0] = (f16)val[0][j]; p[1] = (f16)val[1][j];
                    *(f16x2*)&Bs[(n0+j)*72 + 2*k2] = p;
                }
            } else {
                const float* s0 = Bfb + (long)(k0 + 2*k2)*ldb + bn + n0;
                const float4 u = *(const float4*)s0;
                const float4 v = *(const float4*)(s0 + ldb);
                f16x2 p0, p1, p2, p3;
                p0[0]=(f16)u.x; p0[1]=(f16)v.x;
                p1[0]=(f16)u.y; p1[1]=(f16)v.y;
                p2[0]=(f16)u.z; p2[1]=(f16)v.z;
                p3[0]=(f16)u.w; p3[1]=(f16)v.w;
                *(f16x2*)&Bs[(n0+0)*72 + 2*k2] = p0;
                *(f16x2*)&Bs[(n0+1)*72 + 2*k2] = p1;
                *(f16x2*)&Bs[(n0+2)*72 + 2*k2] = p2;
                *(f16x2*)&Bs[(n0+3)*72 + 2*k2] = p3;
            }
        }
        __syncthreads();
        // ---- MFMA: wave tile 64x64 = 4x4 of 16x16, two k32-steps ----
        const int abase = (w*64 + lane16)*72 + quad*8;
        const int bbase = lane16*72 + quad*8;
        #pragma unroll
        for (int s = 0; s < 2; s++) {
            f16x8 af[4], bf[4];
            #pragma unroll
            for (int i = 0; i < 4; i++) af[i] = *(const f16x8*)&As[abase + i*1152 + s*32];
            #pragma unroll
            for (int j = 0; j < 4; j++) bf[j] = *(const f16x8*)&Bs[bbase + j*1152 + s*32];
            #pragma unroll
            for (int i = 0; i < 4; i++)
                #pragma unroll
                for (int j = 0; j < 4; j++)
                    acc[i][j] = __builtin_amdgcn_mfma_f32_16x16x32_f16(af[i], bf[j], acc[i][j], 0, 0, 0);
        }
        __syncthreads();
    }

    // ---- epilogue ----
    if constexpr (MODE == 0) {
        // transpose acc into LDS tile [64 m][264 h-stride], then coalesced Gt store
        f16* Gl = As;
        #pragma unroll
        for (int i = 0; i < 4; i++)
            #pragma unroll
            for (int r = 0; r < 4; r++) {
                const int h = w*64 + i*16 + quad*4 + r;
                #pragma unroll
                for (int j = 0; j < 4; j++)
                    Gl[(j*16 + lane16)*264 + h] = (f16)acc[i][j][r];
            }
        __syncthreads();
        f16* Gtb = Ch + (long)b*strideC + (long)bn*H_;
        #pragma unroll
        for (int it = 0; it < 8; it++) {
            const int t = it*256 + tid;
            const int m = t >> 5, c = (t & 31)*8;
            *(f16x8*)&Gtb[m*H_ + c] = *(const f16x8*)&Gl[m*264 + c];
        }
    } else {
        if constexpr (MODE == 1) {
            // build P[64 pts][256 h] in LDS from Gt rows (coalesced)
            f16* P = As;
            const int p  = tid >> 2;
            const int qd = tid & 3;
            const long ib = ((long)b*N_ + bn + p)*3;
            const int i0 = idxp[ib], i1 = idxp[ib+1], i2 = idxp[ib+2];
            const float w0 = wgtp[ib], w1 = wgtp[ib+1], w2 = wgtp[ib+2];
            const f16* gb = Gt + (long)b*M_*H_;
            const f16* g0 = gb + (long)i0*H_ + qd*64;
            const f16* g1 = gb + (long)i1*H_ + qd*64;
            const f16* g2 = gb + (long)i2*H_ + qd*64;
            f16* Pr = P + p*264 + qd*64;
            #pragma unroll
            for (int c = 0; c < 64; c += 8) {
                const f16x8 x0 = *(const f16x8*)&g0[c];
                const f16x8 x1 = *(const f16x8*)&g1[c];
                const f16x8 x2 = *(const f16x8*)&g2[c];
                f16x8 o;
                #pragma unroll
                for (int e = 0; e < 8; e++)
                    o[e] = (f16)(w0*(float)x0[e] + w1*(float)x1[e] + w2*(float)x2[e]);
                *(f16x8*)&Pr[c] = o;
            }
            __syncthreads();
            #pragma unroll
            for (int i = 0; i < 4; i++)
                #pragma unroll
                for (int r = 0; r < 4; r++) {
                    const int h = w*64 + i*16 + quad*4 + r;
                    #pragma unroll
                    for (int j = 0; j < 4; j++)
                        acc[i][j][r] += (float)P[(j*16 + lane16)*264 + h];
                }
        }
        const int bid = blockIdx.z * gridDim.x + blockIdx.x;
        float* ps = psum + (long)bid * (2*H_);
        f16* Cb = Ch + (long)b*strideC;
        #pragma unroll
        for (int i = 0; i < 4; i++)
            #pragma unroll
            for (int r = 0; r < 4; r++) {
                const int row = w*64 + i*16 + quad*4 + r;
                float s1 = 0.f, s2 = 0.f;
                #pragma unroll
                for (int j = 0; j < 4; j++) {
                    const float v = acc[i][j][r];
                    s1 += v; s2 += v*v;
                    Cb[(long)row*ldc + bn + j*16 + lane16] = (f16)v;
                }
                #pragma unroll
                for (int off = 1; off < 16; off <<= 1) {
                    s1 += __shfl_xor(s1, off, 64);
                    s2 += __shfl_xor(s2, off, 64);
                }
                if (lane16 == 0) {
                    ps[row]      = s1;
                    ps[H_ + row] = s2;
                }
            }
    }
}

// ---------------------------------------------------------------------------
__global__ __launch_bounds__(256)
void reduce_stats_kernel(const float* __restrict__ psum, float* __restrict__ stats, int nblk)
{
    __shared__ float red[8][33];
    const int o  = blockIdx.x*32 + (threadIdx.x & 31);
    const int ch = threadIdx.x >> 5;
    float s = 0.f;
    for (int bid = ch; bid < nblk; bid += 8)
        s += psum[(long)bid*(2*H_) + o];
    red[ch][threadIdx.x & 31] = s;
    __syncthreads();
    if (ch == 0) {
        float t = 0.f;
        #pragma unroll
        for (int c = 0; c < 8; c++) t += red[c][threadIdx.x & 31];
        stats[o] = t;
    }
}

// ---------------------------------------------------------------------------
__global__ __launch_bounds__(256)
void finalize1_kernel(const float* __restrict__ stats,
                      const float* __restrict__ g, const float* __restrict__ bb,
                      const float* __restrict__ se_rw, const float* __restrict__ se_rb,
                      float* __restrict__ a1, float* __restrict__ c1,
                      float* __restrict__ rw2, float* __restrict__ rbAdj)
{
    __shared__ float cbuf[H_];
    __shared__ float red[256];
    const int o = threadIdx.x;
    const float inv = 1.f / (float)(B_ * N_);
    const float S1 = stats[o], S2 = stats[H_ + o];
    const float mean = S1 * inv;
    const float var  = S2 * inv - mean*mean;
    const float a = g[o] * rsqrtf(var + BN_EPS);
    const float c = bb[o] - mean*a;
    a1[o] = a; c1[o] = c; cbuf[o] = c;
    for (int j = 0; j < SEC_; j++) rw2[j*H_ + o] = se_rw[j*H_ + o] * a;
    __syncthreads();
    for (int j = 0; j < SEC_; j++) {
        red[o] = se_rw[j*H_ + o] * cbuf[o];
        __syncthreads();
        for (int s = 128; s > 0; s >>= 1) {
            if (o < s) red[o] += red[o + s];
            __syncthreads();
        }
        if (o == 0) rbAdj[j] = se_rb[j] + red[0];
        __syncthreads();
    }
}

// ---------------------------------------------------------------------------
__global__ __launch_bounds__(256)
void se_reduce_kernel(const f16* __restrict__ h1h, const float* __restrict__ rw2,
                      float* __restrict__ spart)
{
    constexpr int OCH = H_ / OC_;  // 32
    __shared__ float rwl[SEC_][OCH];
    const int b = blockIdx.y, oc = blockIdx.z;
    const int n0 = blockIdx.x*1024 + threadIdx.x*4;
    for (int i = threadIdx.x; i < SEC_*OCH; i += 256)
        rwl[i/OCH][i%OCH] = rw2[(i/OCH)*H_ + oc*OCH + (i%OCH)];
    __syncthreads();
    f32x4 acc[SEC_];
    #pragma unroll
    for (int j = 0; j < SEC_; j++) acc[j] = (f32x4){0.f,0.f,0.f,0.f};
    const f16* hp = h1h + ((long)b*H_ + oc*OCH)*N_ + n0;
    for (int o = 0; o < OCH; o++) {
        const f16x4 h = *(const f16x4*)(hp + (long)o*N_);
        f32x4 hf; hf[0]=(float)h[0]; hf[1]=(float)h[1]; hf[2]=(float)h[2]; hf[3]=(float)h[3];
        #pragma unroll
        for (int j = 0; j < SEC_; j++) acc[j] += rwl[j][o]*hf;
    }
    #pragma unroll
    for (int j = 0; j < SEC_; j++)
        *(f32x4*)&spart[(((long)oc*B_ + b)*SEC_ + j)*N_ + n0] = acc[j];
}

__global__ __launch_bounds__(256)
void finalize2_kernel(const float* __restrict__ stats,
                      const float* __restrict__ g, const float* __restrict__ bb,
                      float* __restrict__ a2, float* __restrict__ c2)
{
    const int o = threadIdx.x;
    const float inv = 1.f / (float)(B_ * N_);
    const float S1 = stats[o], S2 = stats[H_ + o];
    const float mean = S1 * inv;
    const float var  = S2 * inv - mean*mean;
    const float a = g[o] * rsqrtf(var + BN_EPS);
    a2[o] = a; c2[o] = bb[o] - mean*a;
}

__global__ __launch_bounds__(256)
void bn_relu_kernel(const f16* __restrict__ h2h, float* __restrict__ out,
                    const float* __restrict__ a2, const float* __restrict__ c2)
{
    const long e = ((long)blockIdx.x*256 + threadIdx.x)*8;
    const int o = (int)((e >> 12) & (H_ - 1));
    const f16x8 v = *(const f16x8*)(h2h + e);
    const float a = a2[o], c = c2[o];
    float4 r0, r1;
    r0.x = fmaxf(a*(float)v[0] + c, 0.f);
    r0.y = fmaxf(a*(float)v[1] + c, 0.f);
    r0.z = fmaxf(a*(float)v[2] + c, 0.f);
    r0.w = fmaxf(a*(float)v[3] + c, 0.f);
    r1.x = fmaxf(a*(float)v[4] + c, 0.f);
    r1.y = fmaxf(a*(float)v[5] + c, 0.f);
    r1.z = fmaxf(a*(float)v[6] + c, 0.f);
    r1.w = fmaxf(a*(float)v[7] + c, 0.f);
    *(float4*)(out + e)     = r0;
    *(float4*)(out + e + 4) = r1;
}

// ---------------------------------------------------------------------------
extern "C" void kernel_launch(void* const* d_in, const int* in_sizes, int n_in,
                              void* d_out, int out_size, void* d_ws, size_t ws_size,
                              hipStream_t stream)
{
    const float* unknown = (const float*)d_in[0];
    const float* known   = (const float*)d_in[1];
    const float* uf      = (const float*)d_in[2];
    const float* kf      = (const float*)d_in[3];
    const float* W1      = (const float*)d_in[4];
    const float* g1      = (const float*)d_in[5];
    const float* b1      = (const float*)d_in[6];
    const float* se_rw   = (const float*)d_in[7];
    const float* se_rb   = (const float*)d_in[8];
    const float* se_ew   = (const float*)d_in[9];
    const float* se_eb   = (const float*)d_in[10];
    const float* W2      = (const float*)d_in[11];
    const float* g2      = (const float*)d_in[12];
    const float* b2      = (const float*)d_in[13];

    char* ws = (char*)d_ws;
    size_t off = 0;
    auto alloc = [&](size_t bytes) -> void* {
        void* p = ws + off;
        off += (bytes + 255) & ~(size_t)255;
        return p;
    };
    const int NBLK = (N_/64) * B_;   // 1024 gemm blocks for MODE1/MODE2
    int*   idxp   = (int*)  alloc((size_t)B_*N_*3*4);
    float* wgtp   = (float*)alloc((size_t)B_*N_*3*4);
    f16*   Gt     = (f16*)  alloc((size_t)B_*M_*H_*2);          // 8.4 MB fp16, [b][m][h]
    f16*   h1h    = (f16*)  alloc((size_t)B_*H_*N_*2);          // 33.5 MB fp16
    f16*   h2h    = (f16*)  alloc((size_t)B_*H_*N_*2);          // 33.5 MB fp16
    float* spart  = (float*)alloc((size_t)OC_*B_*SEC_*N_*4);    // 21 MB
    float* psum1  = (float*)alloc((size_t)NBLK*2*H_*4);         // 2 MB
    float* psum2  = (float*)alloc((size_t)NBLK*2*H_*4);         // 2 MB
    float* stats1 = (float*)alloc(2*H_*4);
    float* stats2 = (float*)alloc(2*H_*4);
    float* a1     = (float*)alloc(H_*4);
    float* c1     = (float*)alloc(H_*4);
    float* rw2    = (float*)alloc(SEC_*H_*4);
    float* rbAdj  = (float*)alloc(64*4);
    float* a2     = (float*)alloc(H_*4);
    float* c2     = (float*)alloc(H_*4);
    (void)ws_size; (void)in_sizes; (void)n_in; (void)out_size;

    float* out = (float*)d_out;

    // K1: three_nn (64 queries/block, 4-way m-split, exact ordering)
    three_nn_kernel<<<dim3(N_/64, B_), 256, 0, stream>>>(unknown, known, idxp, wgtp);

    // K2: Gt[b][m][h] = (W1[:, :512] @ kf)^T, fp16
    gemm_mfma<0><<<dim3(M_/64, 1, B_), 256, 0, stream>>>(
        W1, C1_+C2_, kf, nullptr, (long)C2_*M_, M_, C2_,
        Gt, (long)M_*H_, 0,
        nullptr, nullptr, nullptr, nullptr,
        nullptr, nullptr, nullptr, nullptr, nullptr, nullptr);

    // K3: h1 = W1[:, 512:] @ uf + interp(Gt); fp16 store + BN1 partials
    gemm_mfma<1><<<dim3(N_/64, 1, B_), 256, 0, stream>>>(
        W1 + C2_, C1_+C2_, uf, nullptr, (long)C1_*N_, N_, C1_,
        h1h, (long)H_*N_, N_,
        Gt, idxp, wgtp, psum1,
        nullptr, nullptr, nullptr, nullptr, nullptr, nullptr);

    // K3b: reduce partials -> stats1
    reduce_stats_kernel<<<dim3(16), 256, 0, stream>>>(psum1, stats1, NBLK);

    // K4: BN1 finalize + SE fold
    finalize1_kernel<<<1, 256, 0, stream>>>(stats1, g1, b1, se_rw, se_rb, a1, c1, rw2, rbAdj);

    // K5: SE reduce partials
    se_reduce_kernel<<<dim3(N_/1024, B_, OC_), 256, 0, stream>>>(h1h, rw2, spart);

    // K6: conv2 with fused SE expand+sigmoid gate; fp16 store + BN2 partials
    gemm_mfma<2><<<dim3(N_/64, 1, B_), 256, 0, stream>>>(
        W2, H_, nullptr, h1h, (long)H_*N_, N_, H_,
        h2h, (long)H_*N_, N_,
        nullptr, nullptr, nullptr, psum2,
        spart, rbAdj, se_ew, se_eb, a1, c1);

    // K6b: reduce partials -> stats2
    reduce_stats_kernel<<<dim3(16), 256, 0, stream>>>(psum2, stats2, NBLK);

    // K7: BN2 finalize
    finalize2_kernel<<<1, 256, 0, stream>>>(stats2, g2, b2, a2, c2);

    // K8: out = relu(a2*h2 + c2)
    bn_relu_kernel<<<dim3((unsigned)((long)B_*H_*N_/2048)), 256, 0, stream>>>(h2h, out, a2, c2);
}